// Round 1
// baseline (3473.831 us; speedup 1.0000x reference)
//
#include <hip/hip_runtime.h>

#define H_ 256
#define W_ 256
#define CIN_ 64
#define HW_ (H_*W_)

// ---------------------------------------------------------------------------
// prep: transpose w_def (o,c,k) -> wt (k,c,o) so inner o-loop reads contiguous
// ---------------------------------------------------------------------------
__global__ void transpose_wdef(const float* __restrict__ w, float* __restrict__ wt) {
    int idx = blockIdx.x * 256 + threadIdx.x; // 64*64*9 = 36864
    if (idx >= 64 * 64 * 9) return;
    int o = idx / 576;
    int c = (idx / 9) % 64;
    int k = idx % 9;
    wt[k * 4096 + c * 64 + o] = w[idx];
}

// ---------------------------------------------------------------------------
// conv3x3, stride 1, pad 1. One thread = 4 consecutive x-pixels, 1 out channel.
// DECONV: weight is w_deconv[(i,o,2-kh,2-kw)] (flip+transpose), else w[(o,i,kh,kw)].
// ---------------------------------------------------------------------------
template<bool DECONV, bool RELU>
__global__ __launch_bounds__(256) void conv3x3(const float* __restrict__ x,
                                               const float* __restrict__ w,
                                               const float* __restrict__ bias,
                                               float* __restrict__ y,
                                               int Cout) {
    const int W4 = W_ / 4;
    int linear = blockIdx.x * 256 + threadIdx.x;
    int xq = linear % W4;
    int yy = (linear / W4) % H_;
    int o  = (linear / (W4 * H_)) % Cout;
    int b  =  linear / (W4 * H_ * Cout);
    int x0 = xq * 4;

    // column clamps + masks for x0-1 .. x0+4 (zero padding emulation)
    int   xcl[6];
    float xmask[6];
#pragma unroll
    for (int j = 0; j < 6; ++j) {
        int xx = x0 - 1 + j;
        xmask[j] = (xx >= 0 && xx < W_) ? 1.0f : 0.0f;
        xcl[j]   = min(max(xx, 0), W_ - 1);
    }
    int   ycl[3];
    float ymask[3];
#pragma unroll
    for (int kh = 0; kh < 3; ++kh) {
        int yr = yy + kh - 1;
        ymask[kh] = (yr >= 0 && yr < H_) ? 1.0f : 0.0f;
        ycl[kh]   = min(max(yr, 0), H_ - 1);
    }

    float bv = bias[o];
    float acc0 = bv, acc1 = bv, acc2 = bv, acc3 = bv;

    const float* xb = x + (long)b * CIN_ * HW_;
    for (int i = 0; i < CIN_; ++i) {
        const float* xp = xb + (long)i * HW_;
        float wv[9];
        if (DECONV) {
            const float* wp = w + ((long)i * Cout + o) * 9;
#pragma unroll
            for (int kh = 0; kh < 3; ++kh)
#pragma unroll
                for (int kw = 0; kw < 3; ++kw)
                    wv[kh * 3 + kw] = wp[(2 - kh) * 3 + (2 - kw)];
        } else {
            const float* wp = w + ((long)o * CIN_ + i) * 9;
#pragma unroll
            for (int kk = 0; kk < 9; ++kk) wv[kk] = wp[kk];
        }
#pragma unroll
        for (int kh = 0; kh < 3; ++kh) {
            const float* xr = xp + ycl[kh] * W_;
            float xv[6];
#pragma unroll
            for (int j = 0; j < 6; ++j)
                xv[j] = xr[xcl[j]] * (xmask[j] * ymask[kh]);
#pragma unroll
            for (int kw = 0; kw < 3; ++kw) {
                float wk = wv[kh * 3 + kw];
                acc0 = fmaf(xv[kw + 0], wk, acc0);
                acc1 = fmaf(xv[kw + 1], wk, acc1);
                acc2 = fmaf(xv[kw + 2], wk, acc2);
                acc3 = fmaf(xv[kw + 3], wk, acc3);
            }
        }
    }
    if (RELU) {
        acc0 = fmaxf(acc0, 0.f); acc1 = fmaxf(acc1, 0.f);
        acc2 = fmaxf(acc2, 0.f); acc3 = fmaxf(acc3, 0.f);
    }
    float* yp = y + (((long)b * Cout + o) * H_ + yy) * (long)W_ + x0;
    yp[0] = acc0; yp[1] = acc1; yp[2] = acc2; yp[3] = acc3;
}

// ---------------------------------------------------------------------------
// deformable conv 3x3, pad 1. One thread = 1 pixel, all 64 out channels in regs.
// wt layout: [k][c][o] (o contiguous). W_k staged in LDS per k.
// ---------------------------------------------------------------------------
__global__ __launch_bounds__(256) void deform_conv(const float* __restrict__ h,
                                                   const float* __restrict__ off,
                                                   const float* __restrict__ wt,
                                                   const float* __restrict__ bias,
                                                   float* __restrict__ out) {
    __shared__ __align__(16) float wk[4096]; // W_k: [c][o], 16 KB

    int linear = blockIdx.x * 256 + threadIdx.x;
    int x = linear % W_;
    int y = (linear / W_) % H_;
    int b = linear / HW_;

    float acc[64];
#pragma unroll
    for (int o = 0; o < 64; ++o) acc[o] = 0.f;

    const float* hb   = h   + (long)b * CIN_ * HW_;
    const float* offb = off + (long)b * 18 * HW_;

    for (int k = 0; k < 9; ++k) {
        __syncthreads();
#pragma unroll
        for (int t = 0; t < 16; ++t)
            wk[threadIdx.x + t * 256] = wt[k * 4096 + threadIdx.x + t * 256];
        __syncthreads();

        float dy = offb[((2 * k + 0) * H_ + y) * W_ + x];
        float dx = offb[((2 * k + 1) * H_ + y) * W_ + x];
        float py = (float)(y - 1 + k / 3) + dy;
        float px = (float)(x - 1 + k % 3) + dx;
        float y0f = floorf(py), x0f = floorf(px);
        int iy0 = (int)y0f, ix0 = (int)x0f;
        float wy1 = py - y0f, wx1 = px - x0f;
        float wy0 = 1.f - wy1, wx0 = 1.f - wx1;

        bool vy0 = (iy0 >= 0) && (iy0 < H_);
        bool vy1 = (iy0 + 1 >= 0) && (iy0 + 1 < H_);
        bool vx0 = (ix0 >= 0) && (ix0 < W_);
        bool vx1 = (ix0 + 1 >= 0) && (ix0 + 1 < W_);
        int cy0 = min(max(iy0, 0), H_ - 1), cy1 = min(max(iy0 + 1, 0), H_ - 1);
        int cx0 = min(max(ix0, 0), W_ - 1), cx1 = min(max(ix0 + 1, 0), W_ - 1);

        float w00 = wy0 * wx0 * ((vy0 && vx0) ? 1.f : 0.f);
        float w01 = wy0 * wx1 * ((vy0 && vx1) ? 1.f : 0.f);
        float w10 = wy1 * wx0 * ((vy1 && vx0) ? 1.f : 0.f);
        float w11 = wy1 * wx1 * ((vy1 && vx1) ? 1.f : 0.f);

        int f00 = cy0 * W_ + cx0, f01 = cy0 * W_ + cx1;
        int f10 = cy1 * W_ + cx0, f11 = cy1 * W_ + cx1;

        for (int c = 0; c < CIN_; ++c) {
            const float* hp = hb + (long)c * HW_;
            float val = w00 * hp[f00] + w01 * hp[f01]
                      + w10 * hp[f10] + w11 * hp[f11];
            const float* wrow = &wk[c * 64];
#pragma unroll
            for (int o4 = 0; o4 < 16; ++o4) {
                float4 w4 = *(const float4*)(wrow + o4 * 4);
                acc[o4 * 4 + 0] = fmaf(val, w4.x, acc[o4 * 4 + 0]);
                acc[o4 * 4 + 1] = fmaf(val, w4.y, acc[o4 * 4 + 1]);
                acc[o4 * 4 + 2] = fmaf(val, w4.z, acc[o4 * 4 + 2]);
                acc[o4 * 4 + 3] = fmaf(val, w4.w, acc[o4 * 4 + 3]);
            }
        }
    }

    float* ob = out + (long)b * 64 * HW_ + y * W_ + x;
#pragma unroll
    for (int o = 0; o < 64; ++o)
        ob[(long)o * HW_] = fmaxf(acc[o] + bias[o], 0.f);
}

// ---------------------------------------------------------------------------
extern "C" void kernel_launch(void* const* d_in, const int* in_sizes, int n_in,
                              void* d_out, int out_size, void* d_ws, size_t ws_size,
                              hipStream_t stream) {
    const float* x        = (const float*)d_in[0];
    const float* w_deconv = (const float*)d_in[1];
    const float* b_deconv = (const float*)d_in[2];
    const float* w_off    = (const float*)d_in[3];
    const float* b_off    = (const float*)d_in[4];
    const float* w_def    = (const float*)d_in[5];
    const float* b_def    = (const float*)d_in[6];
    float* out = (float*)d_out;

    const int B = 2;
    float* h      = (float*)d_ws;            // B*64*H*W   = 8388608 floats
    float* offset = h + (long)B * 64 * HW_;  // B*18*H*W   = 2359296 floats
    float* wdef_t = offset + (long)B * 18 * HW_; // 36864 floats

    transpose_wdef<<<144, 256, 0, stream>>>(w_def, wdef_t);

    int n1 = B * 64 * H_ * (W_ / 4); // threads for conv1
    conv3x3<true, true><<<n1 / 256, 256, 0, stream>>>(x, w_deconv, b_deconv, h, 64);

    int n2 = B * 18 * H_ * (W_ / 4);
    conv3x3<false, false><<<n2 / 256, 256, 0, stream>>>(h, w_off, b_off, offset, 18);

    deform_conv<<<(B * HW_) / 256, 256, 0, stream>>>(h, offset, wdef_t, b_def, out);
}

// Round 2
// 619.525 us; speedup vs baseline: 5.6073x; 5.6073x over previous
//
#include <hip/hip_runtime.h>

#define H_ 256
#define W_ 256
#define CIN_ 64
#define HW_ (H_*W_)

// ---------------------------------------------------------------------------
// prep: wdef (o,c,k) -> wdeft[k][c][o];  woff (o,i,k) -> wofft[i][k][o(18)]
// ---------------------------------------------------------------------------
__global__ void prep_weights(const float* __restrict__ wdef, float* __restrict__ wdeft,
                             const float* __restrict__ woff, float* __restrict__ wofft) {
    int idx = blockIdx.x * 256 + threadIdx.x;
    if (idx < 64 * 64 * 9) {
        int o = idx / 576, c = (idx / 9) % 64, k = idx % 9;
        wdeft[k * 4096 + c * 64 + o] = wdef[idx];
    }
    if (idx < 18 * 64 * 9) {
        int o = idx / 576, i = (idx / 9) % 64, k = idx % 9;
        wofft[(i * 9 + k) * 18 + o] = woff[idx];
    }
}

// ---------------------------------------------------------------------------
// conv1 (deconv weights, Cout=64, relu). Tile 64x4 px * 64 o per block.
// Thread: 8 px * 8 o.  LDS: x patch 6x66 (stride 73), w [k][64] (stride 68).
// ---------------------------------------------------------------------------
__global__ __launch_bounds__(256, 2) void conv1_kernel(const float* __restrict__ x,
                                                       const float* __restrict__ w,
                                                       const float* __restrict__ bias,
                                                       float* __restrict__ y) {
    __shared__ float xs[6 * 73];
    __shared__ __align__(16) float ws[9 * 68];

    int tid = threadIdx.x;
    int bx = blockIdx.x & 3;          // 4 x-tiles
    int by = (blockIdx.x >> 2) & 63;  // 64 y-tiles
    int b  = blockIdx.x >> 8;         // batch

    int gx  = tid & 7;          // px group
    int r   = (tid >> 3) & 3;   // row in tile
    int go  = tid >> 5;         // o group (0..7)
    int px0l = gx * 8;
    int o0   = go * 8;
    int yy   = by * 4 + r;
    int X0   = bx * 64;

    float acc[8][8];
#pragma unroll
    for (int oo = 0; oo < 8; ++oo) {
        float bv = bias[o0 + oo];
#pragma unroll
        for (int p = 0; p < 8; ++p) acc[oo][p] = bv;
    }

    const float* xb = x + (long)b * CIN_ * HW_;

    for (int i = 0; i < CIN_; ++i) {
        __syncthreads();
        // stage x patch: rows by*4-1 .. by*4+4, cols X0-1 .. X0+64
        const float* xp = xb + (long)i * HW_;
        for (int e = tid; e < 396; e += 256) {
            int rr = e / 66, cc = e % 66;
            int gy = by * 4 + rr - 1;
            int gc = X0 + cc - 1;
            float v = 0.f;
            if (gy >= 0 && gy < H_ && gc >= 0 && gc < W_) v = xp[gy * W_ + gc];
            xs[rr * 73 + cc] = v;
        }
        // stage weights: ws[k'][o] = w[i][o][8-k']  (flip+transpose)
        const float* wp = w + (long)i * 576;
        for (int e = tid; e < 576; e += 256) {
            int o = e / 9, k = e % 9;
            ws[(8 - k) * 68 + o] = wp[e];
        }
        __syncthreads();

#pragma unroll
        for (int kh = 0; kh < 3; ++kh) {
            float xv[10];
#pragma unroll
            for (int j = 0; j < 10; ++j) xv[j] = xs[(r + kh) * 73 + px0l + j];
#pragma unroll
            for (int kw = 0; kw < 3; ++kw) {
                int k = kh * 3 + kw;
                float4 wa = *(const float4*)&ws[k * 68 + o0];
                float4 wb = *(const float4*)&ws[k * 68 + o0 + 4];
#pragma unroll
                for (int p = 0; p < 8; ++p) {
                    float xval = xv[kw + p];
                    acc[0][p] = fmaf(xval, wa.x, acc[0][p]);
                    acc[1][p] = fmaf(xval, wa.y, acc[1][p]);
                    acc[2][p] = fmaf(xval, wa.z, acc[2][p]);
                    acc[3][p] = fmaf(xval, wa.w, acc[3][p]);
                    acc[4][p] = fmaf(xval, wb.x, acc[4][p]);
                    acc[5][p] = fmaf(xval, wb.y, acc[5][p]);
                    acc[6][p] = fmaf(xval, wb.z, acc[6][p]);
                    acc[7][p] = fmaf(xval, wb.w, acc[7][p]);
                }
            }
        }
    }

#pragma unroll
    for (int oo = 0; oo < 8; ++oo) {
        float* yp = y + ((long)(b * 64 + o0 + oo) * H_ + yy) * W_ + X0 + px0l;
        float4 ra = { fmaxf(acc[oo][0], 0.f), fmaxf(acc[oo][1], 0.f),
                      fmaxf(acc[oo][2], 0.f), fmaxf(acc[oo][3], 0.f) };
        float4 rb = { fmaxf(acc[oo][4], 0.f), fmaxf(acc[oo][5], 0.f),
                      fmaxf(acc[oo][6], 0.f), fmaxf(acc[oo][7], 0.f) };
        *(float4*)yp = ra;
        *(float4*)(yp + 4) = rb;
    }
}

// ---------------------------------------------------------------------------
// conv2 (offset conv, Cout=18, no relu). Tile 64x8 px * 18 o per block.
// Thread: 4 px * 9 o.  LDS: x patch 10x66 (stride 73), w [k][18] (stride 20).
// ---------------------------------------------------------------------------
__global__ __launch_bounds__(256, 2) void conv2_kernel(const float* __restrict__ h,
                                                       const float* __restrict__ wofft,
                                                       const float* __restrict__ bias,
                                                       float* __restrict__ off) {
    __shared__ float xs[10 * 73];
    __shared__ float ws[9 * 20];

    int tid = threadIdx.x;
    int bx = blockIdx.x & 3;
    int by = (blockIdx.x >> 2) & 31;  // 32 y-tiles of 8 rows
    int b  = blockIdx.x >> 7;

    int gx = tid & 15;          // 16 px groups of 4
    int r  = (tid >> 4) & 7;
    int go = tid >> 7;          // 0/1
    int px0l = gx * 4;
    int o0   = go * 9;
    int yy   = by * 8 + r;
    int X0   = bx * 64;

    float acc[9][4];
#pragma unroll
    for (int oo = 0; oo < 9; ++oo)
#pragma unroll
        for (int p = 0; p < 4; ++p) acc[oo][p] = 0.f;

    const float* hb = h + (long)b * CIN_ * HW_;

    for (int i = 0; i < CIN_; ++i) {
        __syncthreads();
        const float* hp = hb + (long)i * HW_;
        for (int e = tid; e < 660; e += 256) {
            int rr = e / 66, cc = e % 66;
            int gy = by * 8 + rr - 1;
            int gc = X0 + cc - 1;
            float v = 0.f;
            if (gy >= 0 && gy < H_ && gc >= 0 && gc < W_) v = hp[gy * W_ + gc];
            xs[rr * 73 + cc] = v;
        }
        const float* wp = wofft + (long)i * 162;
        for (int e = tid; e < 162; e += 256) {
            int k = e / 18, o = e % 18;
            ws[k * 20 + o] = wp[e];
        }
        __syncthreads();

#pragma unroll
        for (int kh = 0; kh < 3; ++kh) {
            float xv[6];
#pragma unroll
            for (int j = 0; j < 6; ++j) xv[j] = xs[(r + kh) * 73 + px0l + j];
#pragma unroll
            for (int kw = 0; kw < 3; ++kw) {
                int k = kh * 3 + kw;
#pragma unroll
                for (int oo = 0; oo < 9; ++oo) {
                    float wv = ws[k * 20 + o0 + oo];
#pragma unroll
                    for (int p = 0; p < 4; ++p)
                        acc[oo][p] = fmaf(xv[kw + p], wv, acc[oo][p]);
                }
            }
        }
    }

#pragma unroll
    for (int oo = 0; oo < 9; ++oo) {
        float bv = bias[o0 + oo];
        float* op = off + ((long)(b * 18 + o0 + oo) * H_ + yy) * W_ + X0 + px0l;
        float4 rr = { acc[oo][0] + bv, acc[oo][1] + bv, acc[oo][2] + bv, acc[oo][3] + bv };
        *(float4*)op = rr;
    }
}

// ---------------------------------------------------------------------------
// deform conv. Block = one image row (256 px) * all 64 o.
// 36 chunks = 9 taps x 4 c-groups(16). Phase A: gather+interp -> val LDS tile.
// Phase B: thread = 4 px * 16 o register GEMM from LDS.
// XCD swizzle: consecutive rows land on the same XCD (gather L2 locality).
// ---------------------------------------------------------------------------
__global__ __launch_bounds__(256, 2) void deform_kernel(const float* __restrict__ h,
                                                        const float* __restrict__ off,
                                                        const float* __restrict__ wdeft,
                                                        const float* __restrict__ bias,
                                                        float* __restrict__ out) {
    __shared__ __align__(16) float val_lds[16 * 260];
    __shared__ __align__(16) float wlds[16 * 64];

    int tid = threadIdx.x;
    // XCD-aware: 512 blocks, xcd = bid%8 gets 64 contiguous global rows
    int gy = (blockIdx.x & 7) * 64 + (blockIdx.x >> 3);
    int b = gy >> 8;
    int y = gy & 255;

    int x   = tid;          // gather-phase pixel
    int pxg = tid & 63;     // GEMM-phase px group
    int go  = tid >> 6;     // GEMM-phase o group (0..3)
    int px0 = pxg * 4;
    int o0  = go * 16;

    float acc[16][4];
#pragma unroll
    for (int oo = 0; oo < 16; ++oo)
#pragma unroll
        for (int p = 0; p < 4; ++p) acc[oo][p] = 0.f;

    const float* hb   = h   + (long)b * CIN_ * HW_;
    const float* offb = off + (long)b * 18 * HW_;

    for (int k = 0; k < 9; ++k) {
        // bilinear setup for this thread's gather pixel (once per tap)
        float dy = offb[((2 * k + 0) * H_ + y) * W_ + x];
        float dx = offb[((2 * k + 1) * H_ + y) * W_ + x];
        float py = (float)(y - 1 + k / 3) + dy;
        float px = (float)(x - 1 + k % 3) + dx;
        float y0f = floorf(py), x0f = floorf(px);
        int iy0 = (int)y0f, ix0 = (int)x0f;
        float wy1 = py - y0f, wx1 = px - x0f;
        float wy0 = 1.f - wy1, wx0 = 1.f - wx1;
        bool vy0 = (iy0 >= 0) && (iy0 < H_);
        bool vy1 = (iy0 + 1 >= 0) && (iy0 + 1 < H_);
        bool vx0 = (ix0 >= 0) && (ix0 < W_);
        bool vx1 = (ix0 + 1 >= 0) && (ix0 + 1 < W_);
        int cy0 = min(max(iy0, 0), H_ - 1), cy1 = min(max(iy0 + 1, 0), H_ - 1);
        int cx0 = min(max(ix0, 0), W_ - 1), cx1 = min(max(ix0 + 1, 0), W_ - 1);
        float w00 = wy0 * wx0 * ((vy0 && vx0) ? 1.f : 0.f);
        float w01 = wy0 * wx1 * ((vy0 && vx1) ? 1.f : 0.f);
        float w10 = wy1 * wx0 * ((vy1 && vx0) ? 1.f : 0.f);
        float w11 = wy1 * wx1 * ((vy1 && vx1) ? 1.f : 0.f);
        int f00 = cy0 * W_ + cx0, f01 = cy0 * W_ + cx1;
        int f10 = cy1 * W_ + cx0, f11 = cy1 * W_ + cx1;

        for (int cg = 0; cg < 4; ++cg) {
            int c0 = cg * 16;
            __syncthreads();   // protect LDS from previous chunk's readers
            // stage weight chunk: [cc][o], contiguous in wdeft
            for (int e = tid; e < 1024; e += 256)
                wlds[e] = wdeft[k * 4096 + c0 * 64 + e];
            // stage val tile: this thread's pixel, 16 channels
#pragma unroll 4
            for (int cc = 0; cc < 16; ++cc) {
                const float* hp = hb + (long)(c0 + cc) * HW_;
                float val = w00 * hp[f00] + w01 * hp[f01]
                          + w10 * hp[f10] + w11 * hp[f11];
                val_lds[cc * 260 + x] = val;
            }
            __syncthreads();
            // register GEMM: 4 px * 16 o
#pragma unroll 4
            for (int cc = 0; cc < 16; ++cc) {
                float4 v = *(const float4*)&val_lds[cc * 260 + px0];
                float vv[4] = { v.x, v.y, v.z, v.w };
#pragma unroll
                for (int q = 0; q < 4; ++q) {
                    float4 wq = *(const float4*)&wlds[cc * 64 + o0 + q * 4];
#pragma unroll
                    for (int p = 0; p < 4; ++p) {
                        acc[q * 4 + 0][p] = fmaf(vv[p], wq.x, acc[q * 4 + 0][p]);
                        acc[q * 4 + 1][p] = fmaf(vv[p], wq.y, acc[q * 4 + 1][p]);
                        acc[q * 4 + 2][p] = fmaf(vv[p], wq.z, acc[q * 4 + 2][p]);
                        acc[q * 4 + 3][p] = fmaf(vv[p], wq.w, acc[q * 4 + 3][p]);
                    }
                }
            }
        }
    }

#pragma unroll
    for (int oo = 0; oo < 16; ++oo) {
        int o = o0 + oo;
        float bv = bias[o];
        float* op = out + ((long)(b * 64 + o) * H_ + y) * W_ + px0;
        float4 rr = { fmaxf(acc[oo][0] + bv, 0.f), fmaxf(acc[oo][1] + bv, 0.f),
                      fmaxf(acc[oo][2] + bv, 0.f), fmaxf(acc[oo][3] + bv, 0.f) };
        *(float4*)op = rr;
    }
}

// ---------------------------------------------------------------------------
extern "C" void kernel_launch(void* const* d_in, const int* in_sizes, int n_in,
                              void* d_out, int out_size, void* d_ws, size_t ws_size,
                              hipStream_t stream) {
    const float* x        = (const float*)d_in[0];
    const float* w_deconv = (const float*)d_in[1];
    const float* b_deconv = (const float*)d_in[2];
    const float* w_off    = (const float*)d_in[3];
    const float* b_off    = (const float*)d_in[4];
    const float* w_def    = (const float*)d_in[5];
    const float* b_def    = (const float*)d_in[6];
    float* out = (float*)d_out;

    const int B = 2;
    float* h      = (float*)d_ws;                 // 2*64*65536 floats
    float* offset = h + (long)B * 64 * HW_;       // 2*18*65536 floats
    float* wdeft  = offset + (long)B * 18 * HW_;  // 36864
    float* wofft  = wdeft + 36864;                // 10368

    prep_weights<<<144, 256, 0, stream>>>(w_def, wdeft, w_off, wofft);
    conv1_kernel<<<512, 256, 0, stream>>>(x, w_deconv, b_deconv, h);
    conv2_kernel<<<256, 256, 0, stream>>>(h, wofft, b_off, offset);
    deform_kernel<<<512, 256, 0, stream>>>(h, offset, wdeft, b_def, out);
}

// Round 3
// 405.236 us; speedup vs baseline: 8.5724x; 1.5288x over previous
//
#include <hip/hip_runtime.h>

#define H_ 256
#define W_ 256
#define CIN_ 64
#define HW_ (H_*W_)

// ---------------------------------------------------------------------------
// prep: wdef (o,c,k) -> wdeft[k][c][o];  woff (o,i,k) -> wofft[i][k][o(18)]
// ---------------------------------------------------------------------------
__global__ void prep_weights(const float* __restrict__ wdef, float* __restrict__ wdeft,
                             const float* __restrict__ woff, float* __restrict__ wofft) {
    int idx = blockIdx.x * 256 + threadIdx.x;
    if (idx < 64 * 64 * 9) {
        int o = idx / 576, c = (idx / 9) % 64, k = idx % 9;
        wdeft[k * 4096 + c * 64 + o] = wdef[idx];
    }
    if (idx < 18 * 64 * 9) {
        int o = idx / 576, i = (idx / 9) % 64, k = idx % 9;
        wofft[i * 162 + k * 18 + o] = woff[idx];
    }
}

// ---------------------------------------------------------------------------
// conv1 (deconv weights, Cout=64, relu), x: NCHW, h out: NHWC.
// Tile 32col x 4row x 64o. Grid 1024 (4 blocks/CU). Thread: 4px x 8o.
// ---------------------------------------------------------------------------
__global__ __launch_bounds__(256, 4) void conv1_kernel(const float* __restrict__ x,
                                                       const float* __restrict__ w,
                                                       const float* __restrict__ bias,
                                                       float* __restrict__ h) {
    __shared__ float xs[6 * 35];               // rows 4+2 halo, cols 32+2, stride 35
    __shared__ __align__(16) float ws[9 * 68]; // [k][o], stride 68

    int tid = threadIdx.x;
    int bx = blockIdx.x & 7;          // 8 x-tiles of 32
    int by = (blockIdx.x >> 3) & 63;  // 64 y-tiles of 4
    int b  = blockIdx.x >> 9;

    int gx = tid & 7;           // 8 px-groups of 4
    int r  = (tid >> 3) & 3;    // row in tile
    int go = tid >> 5;          // 8 o-groups of 8
    int px0 = gx * 4;
    int o0  = go * 8;
    int yy  = by * 4 + r;
    int X0  = bx * 32;

    float acc[8][4];
#pragma unroll
    for (int oo = 0; oo < 8; ++oo) {
        float bv = bias[o0 + oo];
#pragma unroll
        for (int p = 0; p < 4; ++p) acc[oo][p] = bv;
    }

    const float* xb = x + (long)b * CIN_ * HW_;

    for (int i = 0; i < CIN_; ++i) {
        __syncthreads();
        const float* xp = xb + (long)i * HW_;
        if (tid < 204) {                        // 6*34 patch elems
            int rr = tid / 34, cc = tid % 34;
            int gy = by * 4 + rr - 1;
            int gc = X0 + cc - 1;
            float v = 0.f;
            if (gy >= 0 && gy < H_ && gc >= 0 && gc < W_) v = xp[gy * W_ + gc];
            xs[rr * 35 + cc] = v;
        }
        const float* wp = w + (long)i * 576;    // w[(i*64+o)*9 + k]
        for (int e = tid; e < 576; e += 256) {
            int o = e / 9, k = e % 9;
            ws[(8 - k) * 68 + o] = wp[e];       // flip both taps
        }
        __syncthreads();

#pragma unroll
        for (int kh = 0; kh < 3; ++kh) {
            float xv[6];
#pragma unroll
            for (int j = 0; j < 6; ++j) xv[j] = xs[(r + kh) * 35 + px0 + j];
#pragma unroll
            for (int kw = 0; kw < 3; ++kw) {
                int k = kh * 3 + kw;
                float4 wa = *(const float4*)&ws[k * 68 + o0];
                float4 wb = *(const float4*)&ws[k * 68 + o0 + 4];
#pragma unroll
                for (int p = 0; p < 4; ++p) {
                    float xval = xv[kw + p];
                    acc[0][p] = fmaf(xval, wa.x, acc[0][p]);
                    acc[1][p] = fmaf(xval, wa.y, acc[1][p]);
                    acc[2][p] = fmaf(xval, wa.z, acc[2][p]);
                    acc[3][p] = fmaf(xval, wa.w, acc[3][p]);
                    acc[4][p] = fmaf(xval, wb.x, acc[4][p]);
                    acc[5][p] = fmaf(xval, wb.y, acc[5][p]);
                    acc[6][p] = fmaf(xval, wb.z, acc[6][p]);
                    acc[7][p] = fmaf(xval, wb.w, acc[7][p]);
                }
            }
        }
    }

    // store NHWC: h[((b*HW + y*W + x)*64 + o]
    float* hb = h + ((long)b * HW_ + (long)yy * W_ + X0 + px0) * 64 + o0;
#pragma unroll
    for (int p = 0; p < 4; ++p) {
        float4 s0 = { fmaxf(acc[0][p], 0.f), fmaxf(acc[1][p], 0.f),
                      fmaxf(acc[2][p], 0.f), fmaxf(acc[3][p], 0.f) };
        float4 s1 = { fmaxf(acc[4][p], 0.f), fmaxf(acc[5][p], 0.f),
                      fmaxf(acc[6][p], 0.f), fmaxf(acc[7][p], 0.f) };
        *(float4*)(hb + (long)p * 64) = s0;
        *(float4*)(hb + (long)p * 64 + 4) = s1;
    }
}

// ---------------------------------------------------------------------------
// conv2 (offset conv, Cout=18), h: NHWC, offset out: NCHW.
// Tile 64col x 4row x 18o. Grid 512. Thread: 2px x 9o. Channel chunks of 16.
// ---------------------------------------------------------------------------
__global__ __launch_bounds__(256, 2) void conv2_kernel(const float* __restrict__ h,
                                                       const float* __restrict__ wofft,
                                                       const float* __restrict__ bias,
                                                       float* __restrict__ off) {
    __shared__ float xs[16][6][68];                 // [cc][row][col] 26.1KB
    __shared__ __align__(16) float ws0[16 * 9 * 12]; // o 0..8   6.9KB
    __shared__ __align__(16) float ws1[16 * 9 * 12]; // o 9..17  6.9KB

    int tid = threadIdx.x;
    int bx = blockIdx.x & 3;          // 4 x-tiles of 64
    int by = (blockIdx.x >> 2) & 63;  // 64 y-tiles of 4
    int b  = blockIdx.x >> 8;

    int pxg = tid & 127;
    int c2  = pxg & 31;        // col-pair
    int row = pxg >> 5;        // 0..3
    int og  = tid >> 7;        // 0/1
    int col0 = c2 * 2;
    int o0   = og * 9;
    int yy   = by * 4 + row;
    int X0   = bx * 64;

    float acc[9][2];
#pragma unroll
    for (int oo = 0; oo < 9; ++oo) { acc[oo][0] = 0.f; acc[oo][1] = 0.f; }

    const float* hb = h + (long)b * HW_ * 64;
    const float* wbase = og ? ws1 : ws0;

    for (int cg = 0; cg < 4; ++cg) {
        int c0 = cg * 16;
        __syncthreads();
        // stage x patch: 6 rows x 66 cols x 16ch, NHWC float4 loads
        for (int e = tid; e < 1584; e += 256) {   // 396 positions * 4 quads
            int pos = e >> 2, q = e & 3;
            int rr = pos / 66, col = pos % 66;
            int gy = by * 4 + rr - 1;
            int gc = X0 + col - 1;
            float4 v = { 0.f, 0.f, 0.f, 0.f };
            if (gy >= 0 && gy < H_ && gc >= 0 && gc < W_)
                v = *(const float4*)&hb[((long)gy * W_ + gc) * 64 + c0 + q * 4];
            xs[q * 4 + 0][rr][col] = v.x;
            xs[q * 4 + 1][rr][col] = v.y;
            xs[q * 4 + 2][rr][col] = v.z;
            xs[q * 4 + 3][rr][col] = v.w;
        }
        // stage weights: wofft[c][k][o18] -> ws0/ws1 [cc][k][12]
        for (int e = tid; e < 2592; e += 256) {
            int cc = e / 162, rem = e % 162;
            int k = rem / 18, o = rem % 18;
            float v = wofft[(long)(c0 + cc) * 162 + rem];
            if (o < 9) ws0[(cc * 9 + k) * 12 + o] = v;
            else       ws1[(cc * 9 + k) * 12 + o - 9] = v;
        }
        __syncthreads();

#pragma unroll 4
        for (int cc = 0; cc < 16; ++cc) {
#pragma unroll
            for (int kh = 0; kh < 3; ++kh) {
                float xv[4];
#pragma unroll
                for (int m = 0; m < 4; ++m) xv[m] = xs[cc][row + kh][col0 + m];
#pragma unroll
                for (int kw = 0; kw < 3; ++kw) {
                    int k = kh * 3 + kw;
                    float4 wA = *(const float4*)&wbase[(cc * 9 + k) * 12];
                    float4 wB = *(const float4*)&wbase[(cc * 9 + k) * 12 + 4];
                    float  w8 = wbase[(cc * 9 + k) * 12 + 8];
                    float wv[9] = { wA.x, wA.y, wA.z, wA.w, wB.x, wB.y, wB.z, wB.w, w8 };
#pragma unroll
                    for (int oo = 0; oo < 9; ++oo) {
                        acc[oo][0] = fmaf(xv[kw + 0], wv[oo], acc[oo][0]);
                        acc[oo][1] = fmaf(xv[kw + 1], wv[oo], acc[oo][1]);
                    }
                }
            }
        }
    }

#pragma unroll
    for (int oo = 0; oo < 9; ++oo) {
        float bv = bias[o0 + oo];
        float* op = off + ((long)(b * 18 + o0 + oo) * H_ + yy) * W_ + X0 + col0;
        float2 rr2 = { acc[oo][0] + bv, acc[oo][1] + bv };
        *(float2*)op = rr2;
    }
}

// ---------------------------------------------------------------------------
// deform conv. h: NHWC. Block = 128px (half row) x 64o. Grid 1024 (4/CU).
// Chunks: 9 taps x 2 c-groups(32). Gather: thread = 1px x 16ch (NHWC float4).
// GEMM: thread = 4px x 8o. XCD swizzle keeps neighboring rows on one XCD.
// ---------------------------------------------------------------------------
__global__ __launch_bounds__(256, 4) void deform_kernel(const float* __restrict__ h,
                                                        const float* __restrict__ off,
                                                        const float* __restrict__ wdeft,
                                                        const float* __restrict__ bias,
                                                        float* __restrict__ out) {
    __shared__ __align__(16) float val_lds[32 * 128]; // [cc][px] 16KB
    __shared__ __align__(16) float wlds[32 * 64];     // [cc][o]   8KB

    int tid = threadIdx.x;
    int linear = (blockIdx.x & 7) * 128 + (blockIdx.x >> 3); // XCD-contiguous rows
    int half = linear & 1;
    int gy = linear >> 1;       // 0..511
    int b = gy >> 8;
    int y = gy & 255;
    int x0 = half * 128;

    int pxl   = tid & 127;      // gather px
    int halfc = tid >> 7;       // gather channel half (16ch)
    int pxg   = tid & 31;       // GEMM px group (4px)
    int og    = tid >> 5;       // GEMM o group (8o)
    int px0   = pxg * 4;
    int o0    = og * 8;
    int xg    = x0 + pxl;

    float acc[8][4];
#pragma unroll
    for (int oo = 0; oo < 8; ++oo)
#pragma unroll
        for (int p = 0; p < 4; ++p) acc[oo][p] = 0.f;

    const float* hb   = h   + (long)b * HW_ * 64;
    const float* offb = off + (long)b * 18 * HW_;

    for (int k = 0; k < 9; ++k) {
        // bilinear setup (gather px), per tap
        float dy = offb[((2 * k + 0) * H_ + y) * W_ + xg];
        float dx = offb[((2 * k + 1) * H_ + y) * W_ + xg];
        float py = (float)(y - 1 + k / 3) + dy;
        float px = (float)(xg - 1 + k % 3) + dx;
        float y0f = floorf(py), x0f = floorf(px);
        int iy0 = (int)y0f, ix0 = (int)x0f;
        float wy1 = py - y0f, wx1 = px - x0f;
        float wy0 = 1.f - wy1, wx0 = 1.f - wx1;
        bool vy0 = (iy0 >= 0) && (iy0 < H_);
        bool vy1 = (iy0 + 1 >= 0) && (iy0 + 1 < H_);
        bool vx0 = (ix0 >= 0) && (ix0 < W_);
        bool vx1 = (ix0 + 1 >= 0) && (ix0 + 1 < W_);
        int cy0 = min(max(iy0, 0), H_ - 1), cy1 = min(max(iy0 + 1, 0), H_ - 1);
        int cx0 = min(max(ix0, 0), W_ - 1), cx1 = min(max(ix0 + 1, 0), W_ - 1);
        float w00 = wy0 * wx0 * ((vy0 && vx0) ? 1.f : 0.f);
        float w01 = wy0 * wx1 * ((vy0 && vx1) ? 1.f : 0.f);
        float w10 = wy1 * wx0 * ((vy1 && vx0) ? 1.f : 0.f);
        float w11 = wy1 * wx1 * ((vy1 && vx1) ? 1.f : 0.f);
        long a00 = ((long)cy0 * W_ + cx0) * 64;
        long a01 = ((long)cy0 * W_ + cx1) * 64;
        long a10 = ((long)cy1 * W_ + cx0) * 64;
        long a11 = ((long)cy1 * W_ + cx1) * 64;

        for (int cg = 0; cg < 2; ++cg) {
            int c0 = cg * 32;
            __syncthreads();
            // stage weight chunk [32c][64o] as float4
            {
                const float4* wsrc = (const float4*)(wdeft + (long)k * 4096 + c0 * 64);
                float4* wdst = (float4*)wlds;
                wdst[tid]       = wsrc[tid];
                wdst[tid + 256] = wsrc[tid + 256];
            }
            // gather 16 channels (this thread's half), NHWC float4 corners
            int cb = c0 + halfc * 16;
#pragma unroll 2
            for (int q = 0; q < 4; ++q) {
                float4 g00 = *(const float4*)&hb[a00 + cb + q * 4];
                float4 g01 = *(const float4*)&hb[a01 + cb + q * 4];
                float4 g10 = *(const float4*)&hb[a10 + cb + q * 4];
                float4 g11 = *(const float4*)&hb[a11 + cb + q * 4];
                int ccb = halfc * 16 + q * 4;
                val_lds[(ccb + 0) * 128 + pxl] = w00 * g00.x + w01 * g01.x + w10 * g10.x + w11 * g11.x;
                val_lds[(ccb + 1) * 128 + pxl] = w00 * g00.y + w01 * g01.y + w10 * g10.y + w11 * g11.y;
                val_lds[(ccb + 2) * 128 + pxl] = w00 * g00.z + w01 * g01.z + w10 * g10.z + w11 * g11.z;
                val_lds[(ccb + 3) * 128 + pxl] = w00 * g00.w + w01 * g01.w + w10 * g10.w + w11 * g11.w;
            }
            __syncthreads();
            // register GEMM: 32cc x 8o x 4px
#pragma unroll 8
            for (int cc = 0; cc < 32; ++cc) {
                float4 v = *(const float4*)&val_lds[cc * 128 + px0];
                float4 wa = *(const float4*)&wlds[cc * 64 + o0];
                float4 wb = *(const float4*)&wlds[cc * 64 + o0 + 4];
                float vv[4] = { v.x, v.y, v.z, v.w };
#pragma unroll
                for (int p = 0; p < 4; ++p) {
                    acc[0][p] = fmaf(vv[p], wa.x, acc[0][p]);
                    acc[1][p] = fmaf(vv[p], wa.y, acc[1][p]);
                    acc[2][p] = fmaf(vv[p], wa.z, acc[2][p]);
                    acc[3][p] = fmaf(vv[p], wa.w, acc[3][p]);
                    acc[4][p] = fmaf(vv[p], wb.x, acc[4][p]);
                    acc[5][p] = fmaf(vv[p], wb.y, acc[5][p]);
                    acc[6][p] = fmaf(vv[p], wb.z, acc[6][p]);
                    acc[7][p] = fmaf(vv[p], wb.w, acc[7][p]);
                }
            }
        }
    }

#pragma unroll
    for (int oo = 0; oo < 8; ++oo) {
        int o = o0 + oo;
        float bv = bias[o];
        float* op = out + ((long)(b * 64 + o) * H_ + y) * W_ + x0 + px0;
        float4 rr = { fmaxf(acc[oo][0] + bv, 0.f), fmaxf(acc[oo][1] + bv, 0.f),
                      fmaxf(acc[oo][2] + bv, 0.f), fmaxf(acc[oo][3] + bv, 0.f) };
        *(float4*)op = rr;
    }
}

// ---------------------------------------------------------------------------
extern "C" void kernel_launch(void* const* d_in, const int* in_sizes, int n_in,
                              void* d_out, int out_size, void* d_ws, size_t ws_size,
                              hipStream_t stream) {
    const float* x        = (const float*)d_in[0];
    const float* w_deconv = (const float*)d_in[1];
    const float* b_deconv = (const float*)d_in[2];
    const float* w_off    = (const float*)d_in[3];
    const float* b_off    = (const float*)d_in[4];
    const float* w_def    = (const float*)d_in[5];
    const float* b_def    = (const float*)d_in[6];
    float* out = (float*)d_out;

    const int B = 2;
    float* h      = (float*)d_ws;                 // NHWC: 2*HW*64 floats
    float* offset = h + (long)B * HW_ * 64;       // NCHW: 2*18*HW
    float* wdeft  = offset + (long)B * 18 * HW_;  // 36864
    float* wofft  = wdeft + 36864;                // 10368

    prep_weights<<<144, 256, 0, stream>>>(w_def, wdeft, w_off, wofft);
    conv1_kernel<<<1024, 256, 0, stream>>>(x, w_deconv, b_deconv, h);
    conv2_kernel<<<512, 256, 0, stream>>>(h, wofft, b_off, offset);
    deform_kernel<<<1024, 256, 0, stream>>>(h, offset, wdeft, b_def, out);
}

// Round 4
// 279.436 us; speedup vs baseline: 12.4316x; 1.4502x over previous
//
#include <hip/hip_runtime.h>

#define H_ 256
#define W_ 256
#define CIN_ 64
#define HW_ (H_*W_)

typedef __attribute__((ext_vector_type(8))) short bf16x8;
typedef __attribute__((ext_vector_type(4))) float f32x4;

// ---- bf16 helpers (RNE pack, cheap unpack) --------------------------------
__device__ __forceinline__ float bflo(unsigned u) { return __builtin_bit_cast(float, u << 16); }
__device__ __forceinline__ float bfhi(unsigned u) { return __builtin_bit_cast(float, u & 0xffff0000u); }
__device__ __forceinline__ unsigned f2bf(float f) {
    unsigned b = __builtin_bit_cast(unsigned, f);
    b += 0x7fffu + ((b >> 16) & 1u);
    return b >> 16;
}
__device__ __forceinline__ void unpack8(uint4 v, float* f) {
    f[0] = bflo(v.x); f[1] = bfhi(v.x); f[2] = bflo(v.y); f[3] = bfhi(v.y);
    f[4] = bflo(v.z); f[5] = bfhi(v.z); f[6] = bflo(v.w); f[7] = bfhi(v.w);
}
__device__ __forceinline__ uint4 pack8(const float* f) {
    uint4 r;
    r.x = f2bf(f[0]) | (f2bf(f[1]) << 16);
    r.y = f2bf(f[2]) | (f2bf(f[3]) << 16);
    r.z = f2bf(f[4]) | (f2bf(f[5]) << 16);
    r.w = f2bf(f[6]) | (f2bf(f[7]) << 16);
    return r;
}

// ---------------------------------------------------------------------------
// prep: wdef (o,c,k) -> wdefb[k][o][c] bf16;  woff (o,i,k) -> wofft[i][k][o]
// ---------------------------------------------------------------------------
__global__ void prep_weights(const float* __restrict__ wdef, unsigned short* __restrict__ wdefb,
                             const float* __restrict__ woff, float* __restrict__ wofft) {
    int idx = blockIdx.x * 256 + threadIdx.x;
    if (idx < 64 * 64 * 9) {
        int o = idx / 576, c = (idx / 9) % 64, k = idx % 9;
        wdefb[((long)k * 64 + o) * 64 + c] = (unsigned short)f2bf(wdef[idx]);
    }
    if (idx < 18 * 64 * 9) {
        int o = idx / 576, i = (idx / 9) % 64, k = idx % 9;
        wofft[i * 162 + k * 18 + o] = woff[idx];
    }
}

// ---------------------------------------------------------------------------
// conv1 (deconv weights, Cout=64, relu), x: NCHW f32, h out: NHWC bf16.
// Tile 32col x 4row x 64o. Grid 1024. Thread: 4px x 8o.
// ---------------------------------------------------------------------------
__global__ __launch_bounds__(256, 4) void conv1_kernel(const float* __restrict__ x,
                                                       const float* __restrict__ w,
                                                       const float* __restrict__ bias,
                                                       unsigned short* __restrict__ h) {
    __shared__ float xs[6 * 35];
    __shared__ __align__(16) float ws[9 * 68];

    int tid = threadIdx.x;
    int bx = blockIdx.x & 7;
    int by = (blockIdx.x >> 3) & 63;
    int b  = blockIdx.x >> 9;

    int gx = tid & 7;
    int r  = (tid >> 3) & 3;
    int go = tid >> 5;
    int px0 = gx * 4;
    int o0  = go * 8;
    int yy  = by * 4 + r;
    int X0  = bx * 32;

    float acc[8][4];
#pragma unroll
    for (int oo = 0; oo < 8; ++oo) {
        float bv = bias[o0 + oo];
#pragma unroll
        for (int p = 0; p < 4; ++p) acc[oo][p] = bv;
    }

    const float* xb = x + (long)b * CIN_ * HW_;

    for (int i = 0; i < CIN_; ++i) {
        __syncthreads();
        const float* xp = xb + (long)i * HW_;
        if (tid < 204) {
            int rr = tid / 34, cc = tid % 34;
            int gy = by * 4 + rr - 1;
            int gc = X0 + cc - 1;
            float v = 0.f;
            if (gy >= 0 && gy < H_ && gc >= 0 && gc < W_) v = xp[gy * W_ + gc];
            xs[rr * 35 + cc] = v;
        }
        const float* wp = w + (long)i * 576;
        for (int e = tid; e < 576; e += 256) {
            int o = e / 9, k = e % 9;
            ws[(8 - k) * 68 + o] = wp[e];
        }
        __syncthreads();

#pragma unroll
        for (int kh = 0; kh < 3; ++kh) {
            float xv[6];
#pragma unroll
            for (int j = 0; j < 6; ++j) xv[j] = xs[(r + kh) * 35 + px0 + j];
#pragma unroll
            for (int kw = 0; kw < 3; ++kw) {
                int k = kh * 3 + kw;
                float4 wa = *(const float4*)&ws[k * 68 + o0];
                float4 wb = *(const float4*)&ws[k * 68 + o0 + 4];
#pragma unroll
                for (int p = 0; p < 4; ++p) {
                    float xval = xv[kw + p];
                    acc[0][p] = fmaf(xval, wa.x, acc[0][p]);
                    acc[1][p] = fmaf(xval, wa.y, acc[1][p]);
                    acc[2][p] = fmaf(xval, wa.z, acc[2][p]);
                    acc[3][p] = fmaf(xval, wa.w, acc[3][p]);
                    acc[4][p] = fmaf(xval, wb.x, acc[4][p]);
                    acc[5][p] = fmaf(xval, wb.y, acc[5][p]);
                    acc[6][p] = fmaf(xval, wb.z, acc[6][p]);
                    acc[7][p] = fmaf(xval, wb.w, acc[7][p]);
                }
            }
        }
    }

    unsigned short* hp = h + (((long)b * HW_ + (long)yy * W_ + X0 + px0) * 64 + o0);
#pragma unroll
    for (int p = 0; p < 4; ++p) {
        float f[8];
#pragma unroll
        for (int oo = 0; oo < 8; ++oo) f[oo] = fmaxf(acc[oo][p], 0.f);
        *(uint4*)(hp + (long)p * 64) = pack8(f);
    }
}

// ---------------------------------------------------------------------------
// conv2 (offset conv, Cout=18), h: NHWC bf16, offset out: NCHW f32.
// Tile 64col x 4row x 18o. Grid 512. Thread: 2px x 9o. Channel chunks of 16.
// ---------------------------------------------------------------------------
__global__ __launch_bounds__(256, 2) void conv2_kernel(const unsigned short* __restrict__ h,
                                                       const float* __restrict__ wofft,
                                                       const float* __restrict__ bias,
                                                       float* __restrict__ off) {
    __shared__ float xs[16][6][68];
    __shared__ __align__(16) float ws0[16 * 9 * 12];
    __shared__ __align__(16) float ws1[16 * 9 * 12];

    int tid = threadIdx.x;
    int bx = blockIdx.x & 3;
    int by = (blockIdx.x >> 2) & 63;
    int b  = blockIdx.x >> 8;

    int pxg = tid & 127;
    int c2  = pxg & 31;
    int row = pxg >> 5;
    int og  = tid >> 7;
    int col0 = c2 * 2;
    int o0   = og * 9;
    int yy   = by * 4 + row;
    int X0   = bx * 64;

    float acc[9][2];
#pragma unroll
    for (int oo = 0; oo < 9; ++oo) { acc[oo][0] = 0.f; acc[oo][1] = 0.f; }

    const unsigned short* hb = h + (long)b * HW_ * 64;
    const float* wbase = og ? ws1 : ws0;

    for (int cg = 0; cg < 4; ++cg) {
        int c0 = cg * 16;
        __syncthreads();
        // stage x patch: 396 positions x 2 bf16-octets
        for (int e = tid; e < 792; e += 256) {
            int pos = e >> 1, h8 = e & 1;
            int rr = pos / 66, col = pos % 66;
            int gy = by * 4 + rr - 1;
            int gc = X0 + col - 1;
            uint4 v = { 0u, 0u, 0u, 0u };
            if (gy >= 0 && gy < H_ && gc >= 0 && gc < W_)
                v = *(const uint4*)&hb[((long)gy * W_ + gc) * 64 + c0 + h8 * 8];
            int cb = h8 * 8;
            xs[cb + 0][rr][col] = bflo(v.x); xs[cb + 1][rr][col] = bfhi(v.x);
            xs[cb + 2][rr][col] = bflo(v.y); xs[cb + 3][rr][col] = bfhi(v.y);
            xs[cb + 4][rr][col] = bflo(v.z); xs[cb + 5][rr][col] = bfhi(v.z);
            xs[cb + 6][rr][col] = bflo(v.w); xs[cb + 7][rr][col] = bfhi(v.w);
        }
        for (int e = tid; e < 2592; e += 256) {
            int cc = e / 162, rem = e % 162;
            int k = rem / 18, o = rem % 18;
            float v = wofft[(long)(c0 + cc) * 162 + rem];
            if (o < 9) ws0[(cc * 9 + k) * 12 + o] = v;
            else       ws1[(cc * 9 + k) * 12 + o - 9] = v;
        }
        __syncthreads();

#pragma unroll 4
        for (int cc = 0; cc < 16; ++cc) {
#pragma unroll
            for (int kh = 0; kh < 3; ++kh) {
                float xv[4];
#pragma unroll
                for (int m = 0; m < 4; ++m) xv[m] = xs[cc][row + kh][col0 + m];
#pragma unroll
                for (int kw = 0; kw < 3; ++kw) {
                    int k = kh * 3 + kw;
                    float4 wA = *(const float4*)&wbase[(cc * 9 + k) * 12];
                    float4 wB = *(const float4*)&wbase[(cc * 9 + k) * 12 + 4];
                    float  w8 = wbase[(cc * 9 + k) * 12 + 8];
                    float wv[9] = { wA.x, wA.y, wA.z, wA.w, wB.x, wB.y, wB.z, wB.w, w8 };
#pragma unroll
                    for (int oo = 0; oo < 9; ++oo) {
                        acc[oo][0] = fmaf(xv[kw + 0], wv[oo], acc[oo][0]);
                        acc[oo][1] = fmaf(xv[kw + 1], wv[oo], acc[oo][1]);
                    }
                }
            }
        }
    }

#pragma unroll
    for (int oo = 0; oo < 9; ++oo) {
        float bv = bias[o0 + oo];
        float* op = off + ((long)(b * 18 + o0 + oo) * H_ + yy) * W_ + X0 + col0;
        float2 rr2 = { acc[oo][0] + bv, acc[oo][1] + bv };
        *(float2*)op = rr2;
    }
}

// ---------------------------------------------------------------------------
// deform conv via MFMA. h: NHWC bf16. Block = 64px x 64o, 4 waves.
// Per tap: gather -> val[64px][64c] bf16 LDS (stride 72), B tile wlds[64o][64c];
// MFMA: wave = 64px x 16o, 4 frags, K=32 per mfma_f32_16x16x32_bf16.
// ---------------------------------------------------------------------------
__global__ __launch_bounds__(256, 4) void deform_mfma(const unsigned short* __restrict__ h,
                                                      const float* __restrict__ off,
                                                      const unsigned short* __restrict__ wdefb,
                                                      const float* __restrict__ bias,
                                                      float* __restrict__ out) {
    __shared__ __align__(16) unsigned short val_lds[64 * 72]; // [px][c] 9216B
    __shared__ __align__(16) unsigned short wlds[64 * 72];    // [o][c]  9216B

    int tid = threadIdx.x;
    // XCD swizzle: each XCD gets 256 consecutive linear tiles (64 rows)
    int linear = (blockIdx.x & 7) * 256 + (blockIdx.x >> 3);
    int b  = linear >> 10;
    int y  = (linear >> 2) & 255;
    int x0 = (linear & 3) * 64;

    // gather-phase ids
    int px = tid & 63;          // pixel in tile
    int cq = tid >> 6;          // 16-ch quad
    int xg = x0 + px;
    // B-stage ids
    int o_s   = tid >> 2;
    int c16_s = (tid & 3) * 16;
    // MFMA ids
    int wave = tid >> 6, lane = tid & 63;
    int n0 = wave * 16;
    int lr = lane & 15, lg = lane >> 4;

    f32x4 acc[4];
#pragma unroll
    for (int m = 0; m < 4; ++m) { acc[m][0] = 0.f; acc[m][1] = 0.f; acc[m][2] = 0.f; acc[m][3] = 0.f; }

    const unsigned short* hb = h + (long)b * HW_ * 64;
    const float* offb = off + (long)b * 18 * HW_;

    float dy = offb[y * W_ + xg];
    float dx = offb[HW_ + y * W_ + xg];

    for (int k = 0; k < 9; ++k) {
        // bilinear setup
        float py = (float)(y - 1 + k / 3) + dy;
        float pxs = (float)(xg - 1 + k % 3) + dx;
        float y0f = floorf(py), x0f = floorf(pxs);
        int iy0 = (int)y0f, ix0 = (int)x0f;
        float wy1 = py - y0f, wx1 = pxs - x0f;
        float wy0 = 1.f - wy1, wx0 = 1.f - wx1;
        bool vy0 = (iy0 >= 0) && (iy0 < H_);
        bool vy1 = (iy0 >= -1) && (iy0 < H_ - 1);
        bool vx0 = (ix0 >= 0) && (ix0 < W_);
        bool vx1 = (ix0 >= -1) && (ix0 < W_ - 1);
        int cy0 = min(max(iy0, 0), H_ - 1), cy1 = min(max(iy0 + 1, 0), H_ - 1);
        int cx0 = min(max(ix0, 0), W_ - 1), cx1 = min(max(ix0 + 1, 0), W_ - 1);
        float w00 = wy0 * wx0 * ((vy0 && vx0) ? 1.f : 0.f);
        float w01 = wy0 * wx1 * ((vy0 && vx1) ? 1.f : 0.f);
        float w10 = wy1 * wx0 * ((vy1 && vx0) ? 1.f : 0.f);
        float w11 = wy1 * wx1 * ((vy1 && vx1) ? 1.f : 0.f);
        long a00 = ((long)cy0 * W_ + cx0) * 64 + cq * 16;
        long a01 = ((long)cy0 * W_ + cx1) * 64 + cq * 16;
        long a10 = ((long)cy1 * W_ + cx0) * 64 + cq * 16;
        long a11 = ((long)cy1 * W_ + cx1) * 64 + cq * 16;

        // issue gather loads (overlap with prev MFMA + barrier)
        uint4 q00a = *(const uint4*)&hb[a00], q00b = *(const uint4*)&hb[a00 + 8];
        uint4 q01a = *(const uint4*)&hb[a01], q01b = *(const uint4*)&hb[a01 + 8];
        uint4 q10a = *(const uint4*)&hb[a10], q10b = *(const uint4*)&hb[a10 + 8];
        uint4 q11a = *(const uint4*)&hb[a11], q11b = *(const uint4*)&hb[a11 + 8];
        // issue B-tile loads
        const unsigned short* wsrc = wdefb + ((long)k * 64 + o_s) * 64 + c16_s;
        uint4 wq0 = *(const uint4*)wsrc;
        uint4 wq1 = *(const uint4*)(wsrc + 8);
        // prefetch next tap's offsets
        float dyn = 0.f, dxn = 0.f;
        if (k < 8) {
            dyn = offb[(2 * k + 2) * HW_ + y * W_ + xg];
            dxn = offb[(2 * k + 3) * HW_ + y * W_ + xg];
        }

        __syncthreads();   // prev MFMA reads done
        *(uint4*)&wlds[o_s * 72 + c16_s]     = wq0;
        *(uint4*)&wlds[o_s * 72 + c16_s + 8] = wq1;
        {
            float g0[8], g1[8], g2[8], g3[8], v8[8];
            unpack8(q00a, g0); unpack8(q01a, g1); unpack8(q10a, g2); unpack8(q11a, g3);
#pragma unroll
            for (int j = 0; j < 8; ++j)
                v8[j] = fmaf(g3[j], w11, fmaf(g2[j], w10, fmaf(g1[j], w01, g0[j] * w00)));
            *(uint4*)&val_lds[px * 72 + cq * 16] = pack8(v8);
            unpack8(q00b, g0); unpack8(q01b, g1); unpack8(q10b, g2); unpack8(q11b, g3);
#pragma unroll
            for (int j = 0; j < 8; ++j)
                v8[j] = fmaf(g3[j], w11, fmaf(g2[j], w10, fmaf(g1[j], w01, g0[j] * w00)));
            *(uint4*)&val_lds[px * 72 + cq * 16 + 8] = pack8(v8);
        }
        __syncthreads();   // tiles ready

        // MFMA phase: wave -> 64px x 16o
        bf16x8 bf0 = *(const bf16x8*)&wlds[(n0 + lr) * 72 + lg * 8];
        bf16x8 bf1 = *(const bf16x8*)&wlds[(n0 + lr) * 72 + 32 + lg * 8];
#pragma unroll
        for (int m = 0; m < 4; ++m) {
            bf16x8 a0 = *(const bf16x8*)&val_lds[(m * 16 + lr) * 72 + lg * 8];
            bf16x8 a1 = *(const bf16x8*)&val_lds[(m * 16 + lr) * 72 + 32 + lg * 8];
            acc[m] = __builtin_amdgcn_mfma_f32_16x16x32_bf16(a0, bf0, acc[m], 0, 0, 0);
            acc[m] = __builtin_amdgcn_mfma_f32_16x16x32_bf16(a1, bf1, acc[m], 0, 0, 0);
        }
        dy = dyn; dx = dxn;
    }

    // epilogue: C/D layout col(o)=lane&15, row(px)=lg*4+reg
    float bv = bias[n0 + lr];
    float* outb = out + ((long)b * 64 + n0 + lr) * HW_ + y * W_ + x0;
#pragma unroll
    for (int m = 0; m < 4; ++m) {
        float4 r = { fmaxf(acc[m][0] + bv, 0.f), fmaxf(acc[m][1] + bv, 0.f),
                     fmaxf(acc[m][2] + bv, 0.f), fmaxf(acc[m][3] + bv, 0.f) };
        *(float4*)(outb + m * 16 + lg * 4) = r;
    }
}

// ---------------------------------------------------------------------------
extern "C" void kernel_launch(void* const* d_in, const int* in_sizes, int n_in,
                              void* d_out, int out_size, void* d_ws, size_t ws_size,
                              hipStream_t stream) {
    const float* x        = (const float*)d_in[0];
    const float* w_deconv = (const float*)d_in[1];
    const float* b_deconv = (const float*)d_in[2];
    const float* w_off    = (const float*)d_in[3];
    const float* b_off    = (const float*)d_in[4];
    const float* w_def    = (const float*)d_in[5];
    const float* b_def    = (const float*)d_in[6];
    float* out = (float*)d_out;

    char* ws = (char*)d_ws;
    unsigned short* hbf  = (unsigned short*)ws;                      // 2*HW*64 bf16 = 33.5MB
    float* offset        = (float*)(ws + 33554432);                  // 2*18*HW f32 = 9.4MB
    unsigned short* wdefb = (unsigned short*)(ws + 33554432 + 9437184); // 36864 bf16
    float* wofft         = (float*)(ws + 33554432 + 9437184 + 73728);   // 10368 f32

    prep_weights<<<144, 256, 0, stream>>>(w_def, wdefb, w_off, wofft);
    conv1_kernel<<<1024, 256, 0, stream>>>(x, w_deconv, b_deconv, hbf);
    conv2_kernel<<<512, 256, 0, stream>>>(hbf, wofft, b_off, offset);
    deform_mfma<<<2048, 256, 0, stream>>>(hbf, offset, wdefb, b_def, out);
}

// Round 5
// 216.034 us; speedup vs baseline: 16.0800x; 1.2935x over previous
//
#include <hip/hip_runtime.h>

#define H_ 256
#define W_ 256
#define HW_ (H_*W_)

typedef __attribute__((ext_vector_type(8))) short bf16x8;
typedef __attribute__((ext_vector_type(4))) float f32x4;

// ---- bf16 helpers (RNE pack, cheap unpack) --------------------------------
__device__ __forceinline__ float bflo(unsigned u) { return __builtin_bit_cast(float, u << 16); }
__device__ __forceinline__ float bfhi(unsigned u) { return __builtin_bit_cast(float, u & 0xffff0000u); }
__device__ __forceinline__ unsigned f2bf(float f) {
    unsigned b = __builtin_bit_cast(unsigned, f);
    b += 0x7fffu + ((b >> 16) & 1u);
    return b >> 16;
}
__device__ __forceinline__ void unpack8(uint4 v, float* f) {
    f[0] = bflo(v.x); f[1] = bfhi(v.x); f[2] = bflo(v.y); f[3] = bfhi(v.y);
    f[4] = bflo(v.z); f[5] = bfhi(v.z); f[6] = bflo(v.w); f[7] = bfhi(v.w);
}
__device__ __forceinline__ uint4 pack8(const float* f) {
    uint4 r;
    r.x = f2bf(f[0]) | (f2bf(f[1]) << 16);
    r.y = f2bf(f[2]) | (f2bf(f[3]) << 16);
    r.z = f2bf(f[4]) | (f2bf(f[5]) << 16);
    r.w = f2bf(f[6]) | (f2bf(f[7]) << 16);
    return r;
}
// zero a fragment when the source column is out of bounds (per-lane cndmask)
__device__ __forceinline__ bf16x8 sel_frag(bf16x8 a, bool v) {
    uint4 u = __builtin_bit_cast(uint4, a);
    u.x = v ? u.x : 0u; u.y = v ? u.y : 0u;
    u.z = v ? u.z : 0u; u.w = v ? u.w : 0u;
    return __builtin_bit_cast(bf16x8, u);
}

// ---------------------------------------------------------------------------
// prep: all weights -> bf16 [k][o][c] tiles.
//   wdefb[k][o64][c64] <- w_def[(o*64+c)*9+k]
//   wdcb [k][o64][c64] <- w_deconv[(c*64+o)*9+(8-k)]   (flip + transpose)
//   woffb[k][o32][c64] <- w_off[(o*64+c)*9+k], zero-padded o>=18
// ---------------------------------------------------------------------------
__global__ void prep_weights(const float* __restrict__ wdef, unsigned short* __restrict__ wdefb,
                             const float* __restrict__ wdc, unsigned short* __restrict__ wdcb,
                             const float* __restrict__ woff, unsigned short* __restrict__ woffb) {
    int idx = blockIdx.x * 256 + threadIdx.x;   // grid covers 36864
    if (idx < 36864) {
        int k = idx >> 12, o = (idx >> 6) & 63, c = idx & 63;
        wdefb[idx] = (unsigned short)f2bf(wdef[(o * 64 + c) * 9 + k]);
        wdcb[idx]  = (unsigned short)f2bf(wdc[(c * 64 + o) * 9 + (8 - k)]);
    }
    if (idx < 18432) {
        int k = idx >> 11, o = (idx >> 6) & 31, c = idx & 63;
        woffb[idx] = (o < 18) ? (unsigned short)f2bf(woff[(o * 64 + c) * 9 + k])
                              : (unsigned short)0;
    }
}

// ---------------------------------------------------------------------------
// x NCHW f32 -> xb NHWC bf16 (LDS transpose, 64px x 64c tiles)
// ---------------------------------------------------------------------------
__global__ __launch_bounds__(256) void x_to_nhwc(const float* __restrict__ x,
                                                 unsigned short* __restrict__ xb) {
    __shared__ unsigned short t[64 * 72];
    int tid = threadIdx.x;
    int b = blockIdx.x >> 10;
    long pxb = (long)(blockIdx.x & 1023) * 64;
    const float* xp = x + (long)b * 64 * HW_ + pxb;
    int px = tid & 63, cg = tid >> 6;
    for (int c = cg; c < 64; c += 4)
        t[px * 72 + c] = (unsigned short)f2bf(xp[(long)c * HW_ + px]);
    __syncthreads();
    int spx = tid >> 2, q = tid & 3;
    unsigned short* dst = xb + ((long)b * HW_ + pxb + spx) * 64 + q * 16;
    *(uint4*)dst       = *(const uint4*)&t[spx * 72 + q * 16];
    *(uint4*)(dst + 8) = *(const uint4*)&t[spx * 72 + q * 16 + 8];
}

// ---------------------------------------------------------------------------
// conv1 via MFMA implicit GEMM. xb: NHWC bf16, h out: NHWC bf16 (+relu+bias).
// Block = 128px x 64o, 4 waves; wave = 128px(m=8) x 16o. No LDS in main loop:
// A-frags loaded straight from global (per-lane 16B), B-frags from wdcb.
// ---------------------------------------------------------------------------
__global__ __launch_bounds__(256, 4) void conv1_mfma(const unsigned short* __restrict__ xb,
                                                     const unsigned short* __restrict__ wdcb,
                                                     const float* __restrict__ bias,
                                                     unsigned short* __restrict__ h) {
    __shared__ unsigned short cs[128 * 72];   // epilogue repack tile

    int tid = threadIdx.x;
    int linear = (blockIdx.x & 7) * 128 + (blockIdx.x >> 3);  // XCD swizzle, 1024 blocks
    int bx = linear & 1;
    int y  = (linear >> 1) & 255;
    int b  = linear >> 9;
    int X0 = bx * 128;

    int wave = tid >> 6, lane = tid & 63;
    int lr = lane & 15, lg = lane >> 4;
    int n0 = wave * 16;

    f32x4 acc[8];
#pragma unroll
    for (int m = 0; m < 8; ++m) { acc[m][0]=0.f; acc[m][1]=0.f; acc[m][2]=0.f; acc[m][3]=0.f; }

    const unsigned short* xbb = xb + (long)b * HW_ * 64;
    const unsigned short* pb  = wdcb + (n0 + lr) * 64 + lg * 8;

    for (int k = 0; k < 9; ++k) {
        int ky = k / 3 - 1, kx = k % 3 - 1;
        int yr = y + ky;
        if (yr < 0 || yr >= H_) continue;          // uniform per block
        bf16x8 b0 = *(const bf16x8*)(pb + k * 4096);
        bf16x8 b1 = *(const bf16x8*)(pb + k * 4096 + 32);
        const unsigned short* xr = xbb + (long)yr * (W_ * 64);
        int cb = X0 + kx;
#pragma unroll
        for (int m = 0; m < 8; ++m) {
            int col  = cb + m * 16 + lr;
            int colc = min(max(col, 0), W_ - 1);
            const unsigned short* ap = xr + colc * 64 + lg * 8;
            bf16x8 a0 = *(const bf16x8*)ap;
            bf16x8 a1 = *(const bf16x8*)(ap + 32);
            bool v = (col == colc);
            a0 = sel_frag(a0, v);
            a1 = sel_frag(a1, v);
            acc[m] = __builtin_amdgcn_mfma_f32_16x16x32_bf16(a0, b0, acc[m], 0, 0, 0);
            acc[m] = __builtin_amdgcn_mfma_f32_16x16x32_bf16(a1, b1, acc[m], 0, 0, 0);
        }
    }

    // epilogue: bias+relu, repack via LDS to NHWC bf16, vector stores
    float bv = bias[n0 + lr];
#pragma unroll
    for (int m = 0; m < 8; ++m)
#pragma unroll
        for (int r = 0; r < 4; ++r) {
            float vv = fmaxf(acc[m][r] + bv, 0.f);
            cs[(m * 16 + lg * 4 + r) * 72 + n0 + lr] = (unsigned short)f2bf(vv);
        }
    __syncthreads();
    int spx = tid >> 1, sc0 = (tid & 1) * 32;
    unsigned short* dst = h + ((long)b * HW_ + (long)y * W_ + X0 + spx) * 64 + sc0;
    const unsigned short* srcp = &cs[spx * 72 + sc0];
#pragma unroll
    for (int q = 0; q < 4; ++q)
        *(uint4*)(dst + q * 8) = *(const uint4*)(srcp + q * 8);
}

// ---------------------------------------------------------------------------
// conv2 via MFMA, N=18 padded to 32. h: NHWC bf16 -> offset: NCHW f32.
// Block = 128px x 32o(18 used), 4 waves: wave = 64px(m=4) x 16o half.
// ---------------------------------------------------------------------------
__global__ __launch_bounds__(256, 4) void conv2_mfma(const unsigned short* __restrict__ h,
                                                     const unsigned short* __restrict__ woffb,
                                                     const float* __restrict__ bias,
                                                     float* __restrict__ off) {
    int tid = threadIdx.x;
    int linear = (blockIdx.x & 7) * 128 + (blockIdx.x >> 3);  // 1024 blocks
    int bx = linear & 1;
    int y  = (linear >> 1) & 255;
    int b  = linear >> 9;

    int wave = tid >> 6, lane = tid & 63;
    int lr = lane & 15, lg = lane >> 4;
    int pxh = wave & 1, nh = wave >> 1;
    int X0 = bx * 128 + pxh * 64;
    int n0 = nh * 16;

    f32x4 acc[4];
#pragma unroll
    for (int m = 0; m < 4; ++m) { acc[m][0]=0.f; acc[m][1]=0.f; acc[m][2]=0.f; acc[m][3]=0.f; }

    const unsigned short* hb = h + (long)b * HW_ * 64;
    const unsigned short* pb = woffb + (n0 + lr) * 64 + lg * 8;

    for (int k = 0; k < 9; ++k) {
        int ky = k / 3 - 1, kx = k % 3 - 1;
        int yr = y + ky;
        if (yr < 0 || yr >= H_) continue;
        bf16x8 b0 = *(const bf16x8*)(pb + k * 2048);
        bf16x8 b1 = *(const bf16x8*)(pb + k * 2048 + 32);
        const unsigned short* xr = hb + (long)yr * (W_ * 64);
        int cb = X0 + kx;
#pragma unroll
        for (int m = 0; m < 4; ++m) {
            int col  = cb + m * 16 + lr;
            int colc = min(max(col, 0), W_ - 1);
            const unsigned short* ap = xr + colc * 64 + lg * 8;
            bf16x8 a0 = *(const bf16x8*)ap;
            bf16x8 a1 = *(const bf16x8*)(ap + 32);
            bool v = (col == colc);
            a0 = sel_frag(a0, v);
            a1 = sel_frag(a1, v);
            acc[m] = __builtin_amdgcn_mfma_f32_16x16x32_bf16(a0, b0, acc[m], 0, 0, 0);
            acc[m] = __builtin_amdgcn_mfma_f32_16x16x32_bf16(a1, b1, acc[m], 0, 0, 0);
        }
    }

    int o = n0 + lr;
    if (o < 18) {
        float bv = bias[o];
        float* op = off + ((long)b * 18 + o) * HW_ + (long)y * W_ + X0;
#pragma unroll
        for (int m = 0; m < 4; ++m) {
            float4 r = { acc[m][0] + bv, acc[m][1] + bv, acc[m][2] + bv, acc[m][3] + bv };
            *(float4*)(op + m * 16 + lg * 4) = r;
        }
    }
}

// ---------------------------------------------------------------------------
// deform conv via MFMA (unchanged from round 4). h: NHWC bf16.
// ---------------------------------------------------------------------------
__global__ __launch_bounds__(256, 4) void deform_mfma(const unsigned short* __restrict__ h,
                                                      const float* __restrict__ off,
                                                      const unsigned short* __restrict__ wdefb,
                                                      const float* __restrict__ bias,
                                                      float* __restrict__ out) {
    __shared__ __align__(16) unsigned short val_lds[64 * 72];
    __shared__ __align__(16) unsigned short wlds[64 * 72];

    int tid = threadIdx.x;
    int linear = (blockIdx.x & 7) * 256 + (blockIdx.x >> 3);
    int b  = linear >> 10;
    int y  = (linear >> 2) & 255;
    int x0 = (linear & 3) * 64;

    int px = tid & 63;
    int cq = tid >> 6;
    int xg = x0 + px;
    int o_s   = tid >> 2;
    int c16_s = (tid & 3) * 16;
    int wave = tid >> 6, lane = tid & 63;
    int n0 = wave * 16;
    int lr = lane & 15, lg = lane >> 4;

    f32x4 acc[4];
#pragma unroll
    for (int m = 0; m < 4; ++m) { acc[m][0]=0.f; acc[m][1]=0.f; acc[m][2]=0.f; acc[m][3]=0.f; }

    const unsigned short* hb = h + (long)b * HW_ * 64;
    const float* offb = off + (long)b * 18 * HW_;

    float dy = offb[y * W_ + xg];
    float dx = offb[HW_ + y * W_ + xg];

    for (int k = 0; k < 9; ++k) {
        float py = (float)(y - 1 + k / 3) + dy;
        float pxs = (float)(xg - 1 + k % 3) + dx;
        float y0f = floorf(py), x0f = floorf(pxs);
        int iy0 = (int)y0f, ix0 = (int)x0f;
        float wy1 = py - y0f, wx1 = pxs - x0f;
        float wy0 = 1.f - wy1, wx0 = 1.f - wx1;
        bool vy0 = (iy0 >= 0) && (iy0 < H_);
        bool vy1 = (iy0 >= -1) && (iy0 < H_ - 1);
        bool vx0 = (ix0 >= 0) && (ix0 < W_);
        bool vx1 = (ix0 >= -1) && (ix0 < W_ - 1);
        int cy0 = min(max(iy0, 0), H_ - 1), cy1 = min(max(iy0 + 1, 0), H_ - 1);
        int cx0 = min(max(ix0, 0), W_ - 1), cx1 = min(max(ix0 + 1, 0), W_ - 1);
        float w00 = wy0 * wx0 * ((vy0 && vx0) ? 1.f : 0.f);
        float w01 = wy0 * wx1 * ((vy0 && vx1) ? 1.f : 0.f);
        float w10 = wy1 * wx0 * ((vy1 && vx0) ? 1.f : 0.f);
        float w11 = wy1 * wx1 * ((vy1 && vx1) ? 1.f : 0.f);
        long a00 = ((long)cy0 * W_ + cx0) * 64 + cq * 16;
        long a01 = ((long)cy0 * W_ + cx1) * 64 + cq * 16;
        long a10 = ((long)cy1 * W_ + cx0) * 64 + cq * 16;
        long a11 = ((long)cy1 * W_ + cx1) * 64 + cq * 16;

        uint4 q00a = *(const uint4*)&hb[a00], q00b = *(const uint4*)&hb[a00 + 8];
        uint4 q01a = *(const uint4*)&hb[a01], q01b = *(const uint4*)&hb[a01 + 8];
        uint4 q10a = *(const uint4*)&hb[a10], q10b = *(const uint4*)&hb[a10 + 8];
        uint4 q11a = *(const uint4*)&hb[a11], q11b = *(const uint4*)&hb[a11 + 8];
        const unsigned short* wsrc = wdefb + ((long)k * 64 + o_s) * 64 + c16_s;
        uint4 wq0 = *(const uint4*)wsrc;
        uint4 wq1 = *(const uint4*)(wsrc + 8);
        float dyn = 0.f, dxn = 0.f;
        if (k < 8) {
            dyn = offb[(2 * k + 2) * HW_ + y * W_ + xg];
            dxn = offb[(2 * k + 3) * HW_ + y * W_ + xg];
        }

        __syncthreads();
        *(uint4*)&wlds[o_s * 72 + c16_s]     = wq0;
        *(uint4*)&wlds[o_s * 72 + c16_s + 8] = wq1;
        {
            float g0[8], g1[8], g2[8], g3[8], v8[8];
            unpack8(q00a, g0); unpack8(q01a, g1); unpack8(q10a, g2); unpack8(q11a, g3);
#pragma unroll
            for (int j = 0; j < 8; ++j)
                v8[j] = fmaf(g3[j], w11, fmaf(g2[j], w10, fmaf(g1[j], w01, g0[j] * w00)));
            *(uint4*)&val_lds[px * 72 + cq * 16] = pack8(v8);
            unpack8(q00b, g0); unpack8(q01b, g1); unpack8(q10b, g2); unpack8(q11b, g3);
#pragma unroll
            for (int j = 0; j < 8; ++j)
                v8[j] = fmaf(g3[j], w11, fmaf(g2[j], w10, fmaf(g1[j], w01, g0[j] * w00)));
            *(uint4*)&val_lds[px * 72 + cq * 16 + 8] = pack8(v8);
        }
        __syncthreads();

        bf16x8 bf0 = *(const bf16x8*)&wlds[(n0 + lr) * 72 + lg * 8];
        bf16x8 bf1 = *(const bf16x8*)&wlds[(n0 + lr) * 72 + 32 + lg * 8];
#pragma unroll
        for (int m = 0; m < 4; ++m) {
            bf16x8 a0 = *(const bf16x8*)&val_lds[(m * 16 + lr) * 72 + lg * 8];
            bf16x8 a1 = *(const bf16x8*)&val_lds[(m * 16 + lr) * 72 + 32 + lg * 8];
            acc[m] = __builtin_amdgcn_mfma_f32_16x16x32_bf16(a0, bf0, acc[m], 0, 0, 0);
            acc[m] = __builtin_amdgcn_mfma_f32_16x16x32_bf16(a1, bf1, acc[m], 0, 0, 0);
        }
        dy = dyn; dx = dxn;
    }

    float bv = bias[n0 + lr];
    float* outb = out + ((long)b * 64 + n0 + lr) * HW_ + y * W_ + x0;
#pragma unroll
    for (int m = 0; m < 4; ++m) {
        float4 r = { fmaxf(acc[m][0] + bv, 0.f), fmaxf(acc[m][1] + bv, 0.f),
                     fmaxf(acc[m][2] + bv, 0.f), fmaxf(acc[m][3] + bv, 0.f) };
        *(float4*)(outb + m * 16 + lg * 4) = r;
    }
}

// ---------------------------------------------------------------------------
extern "C" void kernel_launch(void* const* d_in, const int* in_sizes, int n_in,
                              void* d_out, int out_size, void* d_ws, size_t ws_size,
                              hipStream_t stream) {
    const float* x        = (const float*)d_in[0];
    const float* w_deconv = (const float*)d_in[1];
    const float* b_deconv = (const float*)d_in[2];
    const float* w_off    = (const float*)d_in[3];
    const float* b_off    = (const float*)d_in[4];
    const float* w_def    = (const float*)d_in[5];
    const float* b_def    = (const float*)d_in[6];
    float* out = (float*)d_out;

    char* ws = (char*)d_ws;
    unsigned short* xbb   = (unsigned short*)ws;               // 16,777,216 B
    unsigned short* hbf   = (unsigned short*)(ws + 16777216);  // 16,777,216 B
    float* offset         = (float*)(ws + 33554432);           //  9,437,184 B
    unsigned short* wdcb  = (unsigned short*)(ws + 42991616);  //     73,728 B
    unsigned short* wdefb = (unsigned short*)(ws + 43065344);  //     73,728 B
    unsigned short* woffb = (unsigned short*)(ws + 43139072);  //     36,864 B

    prep_weights<<<144, 256, 0, stream>>>(w_def, wdefb, w_deconv, wdcb, w_off, woffb);
    x_to_nhwc<<<2048, 256, 0, stream>>>(x, xbb);
    conv1_mfma<<<1024, 256, 0, stream>>>(xbb, wdcb, b_deconv, hbf);
    conv2_mfma<<<1024, 256, 0, stream>>>(hbf, woffb, b_off, offset);
    deform_mfma<<<2048, 256, 0, stream>>>(hbf, offset, wdefb, b_def, out);
}

// Round 6
// 140.096 us; speedup vs baseline: 24.7961x; 1.5420x over previous
//
#include <hip/hip_runtime.h>

#define H_ 256
#define W_ 256
#define HW_ (H_*W_)

typedef __attribute__((ext_vector_type(8))) short bf16x8;
typedef __attribute__((ext_vector_type(4))) float f32x4;

// ---- bf16 helpers ----------------------------------------------------------
__device__ __forceinline__ float bflo(unsigned u) { return __builtin_bit_cast(float, u << 16); }
__device__ __forceinline__ float bfhi(unsigned u) { return __builtin_bit_cast(float, u & 0xffff0000u); }
__device__ __forceinline__ unsigned f2bf(float f) {
    unsigned b = __builtin_bit_cast(unsigned, f);
    b += 0x7fffu + ((b >> 16) & 1u);
    return b >> 16;
}
__device__ __forceinline__ unsigned cvtpk(float lo, float hi) {
    unsigned r;
    asm("v_cvt_pk_bf16_f32 %0, %1, %2" : "=v"(r) : "v"(lo), "v"(hi));
    return r;
}
__device__ __forceinline__ void unpack8(uint4 v, float* f) {
    f[0] = bflo(v.x); f[1] = bfhi(v.x); f[2] = bflo(v.y); f[3] = bfhi(v.y);
    f[4] = bflo(v.z); f[5] = bfhi(v.z); f[6] = bflo(v.w); f[7] = bfhi(v.w);
}

// ---------------------------------------------------------------------------
// prep: all weights -> bf16 [k][o][c] tiles.
// ---------------------------------------------------------------------------
__global__ void prep_weights(const float* __restrict__ wdef, unsigned short* __restrict__ wdefb,
                             const float* __restrict__ wdc, unsigned short* __restrict__ wdcb,
                             const float* __restrict__ woff, unsigned short* __restrict__ woffb) {
    int idx = blockIdx.x * 256 + threadIdx.x;   // grid covers 36864
    if (idx < 36864) {
        int k = idx >> 12, o = (idx >> 6) & 63, c = idx & 63;
        wdefb[idx] = (unsigned short)f2bf(wdef[(o * 64 + c) * 9 + k]);
        wdcb[idx]  = (unsigned short)f2bf(wdc[(c * 64 + o) * 9 + (8 - k)]);
    }
    if (idx < 18432) {
        int k = idx >> 11, o = (idx >> 6) & 31, c = idx & 63;
        woffb[idx] = (o < 18) ? (unsigned short)f2bf(woff[(o * 64 + c) * 9 + k])
                              : (unsigned short)0;
    }
}

// ---------------------------------------------------------------------------
// x NCHW f32 -> xb NHWC bf16 (LDS transpose, 64px x 64c tiles)
// ---------------------------------------------------------------------------
__global__ __launch_bounds__(256) void x_to_nhwc(const float* __restrict__ x,
                                                 unsigned short* __restrict__ xb) {
    __shared__ unsigned short t[64 * 72];
    int tid = threadIdx.x;
    int b = blockIdx.x >> 10;
    long pxb = (long)(blockIdx.x & 1023) * 64;
    const float* xp = x + (long)b * 64 * HW_ + pxb;
    int px = tid & 63, cg = tid >> 6;
    for (int c = cg; c < 64; c += 4)
        t[px * 72 + c] = (unsigned short)f2bf(xp[(long)c * HW_ + px]);
    __syncthreads();
    int spx = tid >> 2, q = tid & 3;
    unsigned short* dst = xb + ((long)b * HW_ + pxb + spx) * 64 + q * 16;
    *(uint4*)dst       = *(const uint4*)&t[spx * 72 + q * 16];
    *(uint4*)(dst + 8) = *(const uint4*)&t[spx * 72 + q * 16 + 8];
}

// ---------------------------------------------------------------------------
// row staging: 130 cols (X0-1 .. X0+128) x 64c of an NHWC bf16 row -> LDS,
// zero for OOB cols (conv zero-padding). LDS stride 72 shorts (144B).
// ---------------------------------------------------------------------------
__device__ __forceinline__ void stage_row(const unsigned short* __restrict__ src,
                                          unsigned short* lds, int X0, int tid) {
    for (int e = tid; e < 1040; e += 256) {     // 130 pos x 8 chunks of 16B
        int i = e >> 3, q = e & 7;
        int col = X0 - 1 + i;
        uint4 v = { 0u, 0u, 0u, 0u };
        if (col >= 0 && col < W_) v = *(const uint4*)&src[(long)col * 64 + q * 8];
        *(uint4*)&lds[i * 72 + q * 8] = v;
    }
}

// ---------------------------------------------------------------------------
// conv1 via MFMA, LDS-staged. xb: NHWC bf16 -> h: NHWC bf16 (+bias+relu).
// Block = 128px x 64o, 4 waves; wave = 128px(m=8) x 16o.
// ---------------------------------------------------------------------------
__global__ __launch_bounds__(256, 4) void conv1_mfma(const unsigned short* __restrict__ xb,
                                                     const unsigned short* __restrict__ wdcb,
                                                     const float* __restrict__ bias,
                                                     unsigned short* __restrict__ h) {
    __shared__ __align__(16) unsigned short sA[130 * 72];  // stage + epilogue reuse

    int tid = threadIdx.x;
    int linear = (blockIdx.x & 7) * 128 + (blockIdx.x >> 3);  // XCD swizzle, 1024 blocks
    int bx = linear & 1;
    int y  = (linear >> 1) & 255;
    int b  = linear >> 9;
    int X0 = bx * 128;

    int wave = tid >> 6, lane = tid & 63;
    int lr = lane & 15, lg = lane >> 4;
    int n0 = wave * 16;

    f32x4 acc[8];
#pragma unroll
    for (int m = 0; m < 8; ++m) { acc[m][0]=0.f; acc[m][1]=0.f; acc[m][2]=0.f; acc[m][3]=0.f; }

    const unsigned short* xbb = xb + (long)b * HW_ * 64;
    const unsigned short* pb  = wdcb + (n0 + lr) * 64 + lg * 8;

    for (int ky = 0; ky < 3; ++ky) {
        int yr = y + ky - 1;
        if (yr < 0 || yr >= H_) continue;       // uniform per block
        __syncthreads();                        // prev MFMA reads done
        stage_row(xbb + (long)yr * (W_ * 64), sA, X0, tid);
        __syncthreads();
#pragma unroll
        for (int kx = 0; kx < 3; ++kx) {
            int k = ky * 3 + kx;
            bf16x8 b0 = *(const bf16x8*)(pb + k * 4096);
            bf16x8 b1 = *(const bf16x8*)(pb + k * 4096 + 32);
#pragma unroll
            for (int m = 0; m < 8; ++m) {
                const unsigned short* ap = &sA[(m * 16 + lr + kx) * 72 + lg * 8];
                bf16x8 a0 = *(const bf16x8*)ap;
                bf16x8 a1 = *(const bf16x8*)(ap + 32);
                acc[m] = __builtin_amdgcn_mfma_f32_16x16x32_bf16(a0, b0, acc[m], 0, 0, 0);
                acc[m] = __builtin_amdgcn_mfma_f32_16x16x32_bf16(a1, b1, acc[m], 0, 0, 0);
            }
        }
    }

    // epilogue: bias+relu, repack via LDS (reuse sA) to NHWC bf16
    __syncthreads();
    float bv = bias[n0 + lr];
#pragma unroll
    for (int m = 0; m < 8; ++m)
#pragma unroll
        for (int r = 0; r < 4; ++r) {
            float vv = fmaxf(acc[m][r] + bv, 0.f);
            sA[(m * 16 + lg * 4 + r) * 72 + n0 + lr] = (unsigned short)f2bf(vv);
        }
    __syncthreads();
    int spx = tid >> 1, sc0 = (tid & 1) * 32;
    unsigned short* dst = h + ((long)b * HW_ + (long)y * W_ + X0 + spx) * 64 + sc0;
    const unsigned short* srcp = &sA[spx * 72 + sc0];
#pragma unroll
    for (int q = 0; q < 4; ++q)
        *(uint4*)(dst + q * 8) = *(const uint4*)(srcp + q * 8);
}

// ---------------------------------------------------------------------------
// conv2 via MFMA, LDS-staged, N=18 padded to 32. h NHWC bf16 -> off NCHW f32.
// Block = 128px x 32o, 4 waves; wave = 64px(m=4) x 16o.
// ---------------------------------------------------------------------------
__global__ __launch_bounds__(256, 4) void conv2_mfma(const unsigned short* __restrict__ h,
                                                     const unsigned short* __restrict__ woffb,
                                                     const float* __restrict__ bias,
                                                     float* __restrict__ off) {
    __shared__ __align__(16) unsigned short sA[130 * 72];

    int tid = threadIdx.x;
    int linear = (blockIdx.x & 7) * 128 + (blockIdx.x >> 3);  // 1024 blocks
    int bx = linear & 1;
    int y  = (linear >> 1) & 255;
    int b  = linear >> 9;
    int X0 = bx * 128;

    int wave = tid >> 6, lane = tid & 63;
    int lr = lane & 15, lg = lane >> 4;
    int pxh = wave & 1, nh = wave >> 1;
    int n0 = nh * 16;
    int pxb = pxh * 64;

    f32x4 acc[4];
#pragma unroll
    for (int m = 0; m < 4; ++m) { acc[m][0]=0.f; acc[m][1]=0.f; acc[m][2]=0.f; acc[m][3]=0.f; }

    const unsigned short* hb = h + (long)b * HW_ * 64;
    const unsigned short* pb = woffb + (n0 + lr) * 64 + lg * 8;

    for (int ky = 0; ky < 3; ++ky) {
        int yr = y + ky - 1;
        if (yr < 0 || yr >= H_) continue;
        __syncthreads();
        stage_row(hb + (long)yr * (W_ * 64), sA, X0, tid);
        __syncthreads();
#pragma unroll
        for (int kx = 0; kx < 3; ++kx) {
            int k = ky * 3 + kx;
            bf16x8 b0 = *(const bf16x8*)(pb + k * 2048);
            bf16x8 b1 = *(const bf16x8*)(pb + k * 2048 + 32);
#pragma unroll
            for (int m = 0; m < 4; ++m) {
                const unsigned short* ap = &sA[(pxb + m * 16 + lr + kx) * 72 + lg * 8];
                bf16x8 a0 = *(const bf16x8*)ap;
                bf16x8 a1 = *(const bf16x8*)(ap + 32);
                acc[m] = __builtin_amdgcn_mfma_f32_16x16x32_bf16(a0, b0, acc[m], 0, 0, 0);
                acc[m] = __builtin_amdgcn_mfma_f32_16x16x32_bf16(a1, b1, acc[m], 0, 0, 0);
            }
        }
    }

    int o = n0 + lr;
    if (o < 18) {
        float bv = bias[o];
        float* op = off + ((long)b * 18 + o) * HW_ + (long)y * W_ + X0 + pxb;
#pragma unroll
        for (int m = 0; m < 4; ++m) {
            float4 r = { acc[m][0] + bv, acc[m][1] + bv, acc[m][2] + bv, acc[m][3] + bv };
            *(float4*)(op + m * 16 + lg * 4) = r;
        }
    }
}

// ---------------------------------------------------------------------------
// deform conv via MFMA, 1-barrier-per-tap pipeline, B-frags in registers.
// ---------------------------------------------------------------------------
struct GatherRegs {
    uint4 q00a, q01a, q10a, q11a, q00b, q01b, q10b, q11b;
    float w00, w01, w10, w11;
};

__device__ __forceinline__ GatherRegs gather_issue(const unsigned short* __restrict__ hb,
                                                   int k, int y, int xg,
                                                   float dy, float dx, int cq) {
    GatherRegs g;
    float py  = (float)(y - 1 + k / 3) + dy;
    float pxs = (float)(xg - 1 + k % 3) + dx;
    float y0f = floorf(py), x0f = floorf(pxs);
    int iy0 = (int)y0f, ix0 = (int)x0f;
    float wy1 = py - y0f, wx1 = pxs - x0f;
    float wy0 = 1.f - wy1, wx0 = 1.f - wx1;
    bool vy0 = (iy0 >= 0) && (iy0 < H_);
    bool vy1 = (iy0 >= -1) && (iy0 < H_ - 1);
    bool vx0 = (ix0 >= 0) && (ix0 < W_);
    bool vx1 = (ix0 >= -1) && (ix0 < W_ - 1);
    int cy0 = min(max(iy0, 0), H_ - 1), cy1 = min(max(iy0 + 1, 0), H_ - 1);
    int cx0 = min(max(ix0, 0), W_ - 1), cx1 = min(max(ix0 + 1, 0), W_ - 1);
    g.w00 = wy0 * wx0 * ((vy0 && vx0) ? 1.f : 0.f);
    g.w01 = wy0 * wx1 * ((vy0 && vx1) ? 1.f : 0.f);
    g.w10 = wy1 * wx0 * ((vy1 && vx0) ? 1.f : 0.f);
    g.w11 = wy1 * wx1 * ((vy1 && vx1) ? 1.f : 0.f);
    long a00 = ((long)cy0 * W_ + cx0) * 64 + cq * 16;
    long a01 = ((long)cy0 * W_ + cx1) * 64 + cq * 16;
    long a10 = ((long)cy1 * W_ + cx0) * 64 + cq * 16;
    long a11 = ((long)cy1 * W_ + cx1) * 64 + cq * 16;
    g.q00a = *(const uint4*)&hb[a00]; g.q00b = *(const uint4*)&hb[a00 + 8];
    g.q01a = *(const uint4*)&hb[a01]; g.q01b = *(const uint4*)&hb[a01 + 8];
    g.q10a = *(const uint4*)&hb[a10]; g.q10b = *(const uint4*)&hb[a10 + 8];
    g.q11a = *(const uint4*)&hb[a11]; g.q11b = *(const uint4*)&hb[a11 + 8];
    return g;
}

__device__ __forceinline__ void interp_store(const GatherRegs& g, unsigned short* dst) {
    float g0[8], g1[8], g2[8], g3[8], v8[8];
    unpack8(g.q00a, g0); unpack8(g.q01a, g1); unpack8(g.q10a, g2); unpack8(g.q11a, g3);
#pragma unroll
    for (int j = 0; j < 8; ++j)
        v8[j] = fmaf(g3[j], g.w11, fmaf(g2[j], g.w10, fmaf(g1[j], g.w01, g0[j] * g.w00)));
    uint4 p0 = { cvtpk(v8[0], v8[1]), cvtpk(v8[2], v8[3]),
                 cvtpk(v8[4], v8[5]), cvtpk(v8[6], v8[7]) };
    *(uint4*)dst = p0;
    unpack8(g.q00b, g0); unpack8(g.q01b, g1); unpack8(g.q10b, g2); unpack8(g.q11b, g3);
#pragma unroll
    for (int j = 0; j < 8; ++j)
        v8[j] = fmaf(g3[j], g.w11, fmaf(g2[j], g.w10, fmaf(g1[j], g.w01, g0[j] * g.w00)));
    uint4 p1 = { cvtpk(v8[0], v8[1]), cvtpk(v8[2], v8[3]),
                 cvtpk(v8[4], v8[5]), cvtpk(v8[6], v8[7]) };
    *(uint4*)(dst + 8) = p1;
}

__global__ __launch_bounds__(256, 4) void deform_mfma(const unsigned short* __restrict__ h,
                                                      const float* __restrict__ off,
                                                      const unsigned short* __restrict__ wdefb,
                                                      const float* __restrict__ bias,
                                                      float* __restrict__ out) {
    __shared__ __align__(16) unsigned short val_lds[2][64 * 72];  // 18.4KB double buffer

    int tid = threadIdx.x;
    int linear = (blockIdx.x & 7) * 256 + (blockIdx.x >> 3);  // 2048 blocks, XCD swizzle
    int b  = linear >> 10;
    int y  = (linear >> 2) & 255;
    int x0 = (linear & 3) * 64;

    int px = tid & 63;          // gather pixel
    int cq = tid >> 6;          // 16-ch quad
    int xg = x0 + px;
    int wave = tid >> 6, lane = tid & 63;
    int n0 = wave * 16;
    int lr = lane & 15, lg = lane >> 4;

    f32x4 acc[4];
#pragma unroll
    for (int m = 0; m < 4; ++m) { acc[m][0]=0.f; acc[m][1]=0.f; acc[m][2]=0.f; acc[m][3]=0.f; }

    const unsigned short* hb   = h + (long)b * HW_ * 64;
    const float* offb = off + (long)b * 18 * HW_;
    const unsigned short* bsrc = wdefb + (n0 + lr) * 64 + lg * 8;

    // prologue: tap 0 gathers + B-frags
    float dy = offb[y * W_ + xg];
    float dx = offb[HW_ + y * W_ + xg];
    GatherRegs g = gather_issue(hb, 0, y, xg, dy, dx, cq);
    bf16x8 bc0 = *(const bf16x8*)bsrc;
    bf16x8 bc1 = *(const bf16x8*)(bsrc + 32);

    for (int k = 0; k < 9; ++k) {
        unsigned short* dst = &val_lds[k & 1][px * 72 + cq * 16];
        interp_store(g, dst);               // consume tap-k gathers -> LDS

        GatherRegs gn;                      // issue tap k+1 (overlaps MFMA below)
        bf16x8 bn0, bn1;
        if (k < 8) {
            float dyn = offb[(2 * k + 2) * HW_ + y * W_ + xg];
            float dxn = offb[(2 * k + 3) * HW_ + y * W_ + xg];
            gn = gather_issue(hb, k + 1, y, xg, dyn, dxn, cq);
            bn0 = *(const bf16x8*)(bsrc + (k + 1) * 4096);
            bn1 = *(const bf16x8*)(bsrc + (k + 1) * 4096 + 32);
        }

        __syncthreads();                    // tap-k tile ready

        const unsigned short* vb = val_lds[k & 1];
#pragma unroll
        for (int m = 0; m < 4; ++m) {
            bf16x8 a0 = *(const bf16x8*)&vb[(m * 16 + lr) * 72 + lg * 8];
            bf16x8 a1 = *(const bf16x8*)&vb[(m * 16 + lr) * 72 + 32 + lg * 8];
            acc[m] = __builtin_amdgcn_mfma_f32_16x16x32_bf16(a0, bc0, acc[m], 0, 0, 0);
            acc[m] = __builtin_amdgcn_mfma_f32_16x16x32_bf16(a1, bc1, acc[m], 0, 0, 0);
        }
        g = gn; bc0 = bn0; bc1 = bn1;
    }

    float bv = bias[n0 + lr];
    float* outb = out + ((long)b * 64 + n0 + lr) * HW_ + y * W_ + x0;
#pragma unroll
    for (int m = 0; m < 4; ++m) {
        float4 r = { fmaxf(acc[m][0] + bv, 0.f), fmaxf(acc[m][1] + bv, 0.f),
                     fmaxf(acc[m][2] + bv, 0.f), fmaxf(acc[m][3] + bv, 0.f) };
        *(float4*)(outb + m * 16 + lg * 4) = r;
    }
}

// ---------------------------------------------------------------------------
extern "C" void kernel_launch(void* const* d_in, const int* in_sizes, int n_in,
                              void* d_out, int out_size, void* d_ws, size_t ws_size,
                              hipStream_t stream) {
    const float* x        = (const float*)d_in[0];
    const float* w_deconv = (const float*)d_in[1];
    const float* b_deconv = (const float*)d_in[2];
    const float* w_off    = (const float*)d_in[3];
    const float* b_off    = (const float*)d_in[4];
    const float* w_def    = (const float*)d_in[5];
    const float* b_def    = (const float*)d_in[6];
    float* out = (float*)d_out;

    char* ws = (char*)d_ws;
    unsigned short* xbb   = (unsigned short*)ws;               // 16,777,216 B
    unsigned short* hbf   = (unsigned short*)(ws + 16777216);  // 16,777,216 B
    float* offset         = (float*)(ws + 33554432);           //  9,437,184 B
    unsigned short* wdcb  = (unsigned short*)(ws + 42991616);  //     73,728 B
    unsigned short* wdefb = (unsigned short*)(ws + 43065344);  //     73,728 B
    unsigned short* woffb = (unsigned short*)(ws + 43139072);  //     36,864 B

    prep_weights<<<144, 256, 0, stream>>>(w_def, wdefb, w_deconv, wdcb, w_off, woffb);
    x_to_nhwc<<<2048, 256, 0, stream>>>(x, xbb);
    conv1_mfma<<<1024, 256, 0, stream>>>(xbb, wdcb, b_deconv, hbf);
    conv2_mfma<<<1024, 256, 0, stream>>>(hbf, woffb, b_off, offset);
    deform_mfma<<<2048, 256, 0, stream>>>(hbf, offset, wdefb, b_def, out);
}